// Round 14
// baseline (6635.974 us; speedup 1.0000x reference)
//
#include <hip/hip_runtime.h>
#include <stdint.h>

// Online Neural CDE — R14: zero-sync (R13) + overlap levers.
// 1 batch = 1 block = 1 CU; 128 blocks x 1024 threads (4 waves/SIMD).
// int16 weights (per-row scales) + fp32 activations/state (R13 numerics,
// absmax 20.8 passed). Streams v_win/v_wmid[1]/v_wout from XCD L2 each eval;
// m0 LDS-resident. NEW: in-loop barriers are lgkm-only (global loads stay in
// flight across phases — __syncthreads' vmcnt(0) drain was serializing
// stream vs compute), 1024 threads for latency hiding, register prefetch of
// next-phase weights across barriers, improved m0 bank swizzle.

#define NB   128
#define NTHR 1024

// d_ws byte layout (total 1,387,520 B)
#define SC_OFF   0u        // 2816 f32: wv[0..255] m1[256..511] l4[512..2559] m0[2560..2815]
#define WV_OFF   11264u
#define WM1_OFF  76800u
#define WL4_OFF  207872u
#define WM0_OFF  1256448u

static __device__ __forceinline__ float qmac2(uint32_t q, float h0, float h1, float acc) {
  acc = fmaf((float)(short)(q & 0xffffu), h0, acc);
  return fmaf((float)(short)(q >> 16), h1, acc);
}

// precise softplus: max(x,0) + log1p(exp(-|x|))
static __device__ __forceinline__ float sp(float x) {
  return fmaxf(x, 0.f) + log1pf(expf(-fabsf(x)));
}

// LDS-only barrier: orders all LDS traffic, leaves global loads in flight.
static __device__ __forceinline__ void lbar() {
  asm volatile("s_waitcnt lgkmcnt(0)\n\ts_barrier" ::: "memory");
}

// np.searchsorted(kn, t, 'right') - 1, clipped to [0, 62]; 64 knots.
static __device__ __forceinline__ int seg_idx(const float* kn, float t) {
  int lo = 0, hi = 64;
  while (lo < hi) { int mid = (lo + hi) >> 1; if (kn[mid] <= t) lo = mid + 1; else hi = mid; }
  int jj = lo - 1;
  return jj < 0 ? 0 : (jj > 62 ? 62 : jj);
}

// ---- prep: per-row int16 quantization into 1024-lane chunk-tiled layouts ----
// rows: [0,256) v_win | [256,512) v_wmid[1] | [512,2560) v_wout | [2560,2816) v_wmid[0]
__global__ void prep_kernel(const float* __restrict__ v_win,
                            const float* __restrict__ v_wmid,
                            const float* __restrict__ v_wout,
                            unsigned char* __restrict__ wsb) {
  float* scales = (float*)(wsb + SC_OFF);
  short* wv  = (short*)(wsb + WV_OFF);
  short* wm1 = (short*)(wsb + WM1_OFF);
  short* wl4 = (short*)(wsb + WL4_OFF);
  short* wm0 = (short*)(wsb + WM0_OFF);
  const int r = blockIdx.x, lane = threadIdx.x;
  const float* src;
  int n;
  if (r < 256)       { src = v_win  + (size_t)r * 128;                 n = 128; }
  else if (r < 512)  { src = v_wmid + 65536 + (size_t)(r - 256) * 256; n = 256; }
  else if (r < 2560) { src = v_wout + (size_t)(r - 512) * 256;         n = 256; }
  else               { src = v_wmid + (size_t)(r - 2560) * 256;        n = 256; }
  float m = 0.f;
  for (int i = lane; i < n; i += 64) m = fmaxf(m, fabsf(src[i]));
#pragma unroll
  for (int off = 32; off; off >>= 1) m = fmaxf(m, __shfl_xor(m, off));
  const float inv = (m > 0.f) ? 32767.f / m : 0.f;
  if (lane == 0) scales[r] = (m > 0.f) ? m / 32767.f : 1.f;
  for (int i = lane; i < n; i += 64) {
    short qv = (short)rintf(src[i] * inv);
    if (r < 256) {
      int t = r * 4 + (i >> 5), c = (i & 31) >> 3, e = i & 7;
      wv[c * 8192 + t * 8 + e] = qv;
    } else if (r < 512) {
      int row = r - 256;
      int t = row * 4 + (i >> 6), c = (i & 63) >> 3, e = i & 7;
      wm1[c * 8192 + t * 8 + e] = qv;
    } else if (r < 2560) {
      int row = r - 512;
      int t = row >> 1, c = (row & 1) * 32 + (i >> 3), e = i & 7;
      wl4[(size_t)c * 8192 + t * 8 + e] = qv;
    } else {
      int row = r - 2560;
      wm0[(size_t)row * 256 + i] = qv;
    }
  }
}

__global__ void __launch_bounds__(NTHR)
ncde_kernel(const float* __restrict__ ts, const float* __restrict__ tsi,
            const float* __restrict__ obs, const float* __restrict__ tmax,
            const float* __restrict__ i_win, const float* __restrict__ i_bin,
            const float* __restrict__ i_wmid, const float* __restrict__ i_bmid,
            const float* __restrict__ i_wout, const float* __restrict__ i_bout,
            const float* __restrict__ v_bin, const float* __restrict__ v_bmid,
            const float* __restrict__ v_bout,
            const unsigned char* __restrict__ wsb, float* __restrict__ out) {
  __shared__ __align__(16) uint32_t s_m0[256][132];  // int16-pair m0, swizzled
  __shared__ __align__(16) float s_yin[128];
  __shared__ __align__(16) float s_h1[256];
  __shared__ __align__(16) float s_h2[256];
  __shared__ __align__(16) float s_h3[256];
  __shared__ __align__(16) float s_ts[64];
  __shared__ __align__(16) float s_kn[64];
  __shared__ float s_dx[16];
  __shared__ float s_x0[16];
  __shared__ unsigned char s_sj[128];

  const int t = threadIdx.x;
  const int b = blockIdx.x;
  const int o2 = t >> 2, q = t & 3;        // L1/m0/m1 map
  const int hq = t >> 3, dq = t & 7;       // L4 map (2 rows/thread)
  const bool owner = (dq == 0);

  const float* scales = (const float*)(wsb + SC_OFF);
  const uint4* wvp  = ((const uint4*)(wsb + WV_OFF)) + t;
  const uint4* wm1p = ((const uint4*)(wsb + WM1_OFF)) + t;
  const uint4* wl4p = ((const uint4*)(wsb + WL4_OFF)) + t;

  if (t < 64) { s_ts[t] = ts[b * 64 + t]; s_kn[t] = tsi[b * 64 + t]; }
  const float tm = tmax[b];
  const float bl1 = v_bin[o2];
  const float bm0 = v_bmid[o2];
  const float bm1 = v_bmid[256 + o2];
  const float sc_wv = scales[o2];
  const float sc_m1 = scales[256 + o2];
  const float sc_m0 = scales[2560 + o2];
  const float2 scl4 = *(const float2*)(scales + 512 + 2 * t);
  const float2 vb2  = *(const float2*)(v_bout + 2 * t);
  __syncthreads();

  // m0 -> LDS; col swizzle: row-group XOR + col-group XOR (quartet spread)
  {
    const uint32_t* wm0u = (const uint32_t*)(wsb + WM0_OFF);
    for (int idx = t; idx < 32768; idx += NTHR) {
      int row = idx >> 7, k = idx & 127;
      int kk = k ^ (((row >> 3) & 3) << 2) ^ (((k >> 5) & 3) << 2);
      s_m0[row][kk] = wm0u[idx];
    }
  }
  if (t < 127) {
    int li = t >> 1;
    float te = (t & 1) ? fmaf(0.5f, s_ts[li + 1] - s_ts[li], s_ts[li]) : s_ts[li];
    s_sj[t] = (unsigned char)seg_idx(s_kn, te);
  }
  __syncthreads();

  // ---------------- init MLP: y0 = MLP_i(x0) (one-time, fp32 weights) ------
  if (t < 16) {
    float t0 = s_ts[0];
    int sj = s_sj[0];
    float k0 = s_kn[sj], k1 = s_kn[sj + 1];
    float fr = (t0 - k0) / (k1 - k0);
    const float* ob = obs + ((size_t)b * 64 + sj) * 16 + t;
    s_x0[t] = fmaf(fr, ob[16] - ob[0], ob[0]);
  }
  __syncthreads();
  if (t < 256) {                       // L1i: row t, 16 ins
    float acc = i_bin[t];
    const float* wr = i_win + (size_t)t * 16;
#pragma unroll
    for (int i = 0; i < 16; ++i) acc = fmaf(wr[i], s_x0[i], acc);
    s_h1[t] = sp(acc);
  }
  __syncthreads();
  {                                    // m0i: row o2, quarter q (64 ins)
    float acc = 0.f;
    const float4* wq = (const float4*)(i_wmid + (size_t)o2 * 256 + q * 64);
    const float4* hp = (const float4*)(s_h1 + q * 64);
#pragma unroll
    for (int i = 0; i < 16; ++i) {
      float4 w = wq[i]; float4 hh = hp[i];
      acc = fmaf(w.x, hh.x, acc); acc = fmaf(w.y, hh.y, acc);
      acc = fmaf(w.z, hh.z, acc); acc = fmaf(w.w, hh.w, acc);
    }
    acc += __shfl_xor(acc, 1);
    acc += __shfl_xor(acc, 2);
    if (q == 0) s_h2[o2] = sp(acc + i_bmid[o2]);
  }
  __syncthreads();
  {                                    // m1i
    float acc = 0.f;
    const float4* wq = (const float4*)(i_wmid + 65536 + (size_t)o2 * 256 + q * 64);
    const float4* hp = (const float4*)(s_h2 + q * 64);
#pragma unroll
    for (int i = 0; i < 16; ++i) {
      float4 w = wq[i]; float4 hh = hp[i];
      acc = fmaf(w.x, hh.x, acc); acc = fmaf(w.y, hh.y, acc);
      acc = fmaf(w.z, hh.z, acc); acc = fmaf(w.w, hh.w, acc);
    }
    acc += __shfl_xor(acc, 1);
    acc += __shfl_xor(acc, 2);
    if (q == 0) s_h3[o2] = sp(acc + i_bmid[256 + o2]);
  }
  __syncthreads();
  float yreg = 0.f, kreg = 0.f, kacc = 0.f;
  {                                    // L4i: row hq (128 rows), 8-lane split
    float acc = 0.f;
    const float4* wq = (const float4*)(i_wout + (size_t)hq * 256 + dq * 32);
    const float4* hp = (const float4*)(s_h3 + dq * 32);
#pragma unroll
    for (int i = 0; i < 8; ++i) {
      float4 w = wq[i]; float4 hh = hp[i];
      acc = fmaf(w.x, hh.x, acc); acc = fmaf(w.y, hh.y, acc);
      acc = fmaf(w.z, hh.z, acc); acc = fmaf(w.w, hh.w, acc);
    }
    acc += __shfl_xor(acc, 1);
    acc += __shfl_xor(acc, 2);
    acc += __shfl_xor(acc, 4);
    if (owner) {
      yreg = acc + i_bout[hq];
      out[(size_t)b * 8192 + hq] = (s_ts[0] <= tm) ? yreg : -99.f;
    }
  }
  __syncthreads();

  // ---------------- RK4 over 63 intervals, fully block-local ---------------
  const int m0sw = (((o2 >> 3) & 3) << 2) ^ (q << 2);
#pragma unroll 1
  for (int l = 0; l < 63; ++l) {
    const float tl1 = s_ts[l + 1];
    const float dt = tl1 - s_ts[l];
#pragma unroll 1
    for (int e = 0; e < 4; ++e) {
      // phase 0: owners publish y_in; 16 lanes compute dx(t_e)
      if (owner) {
        float ce = (e == 0) ? 0.f : ((e == 3) ? 1.f : 0.5f);
        s_yin[hq] = fmaf(ce * dt, kreg, yreg);
      }
      if (t < 16) {
        int ti = 2 * l + ((e == 0) ? 0 : ((e == 3) ? 2 : 1));
        int sj = s_sj[ti];
        const float* ob = obs + ((size_t)b * 64 + sj) * 16 + t;
        s_dx[t] = (ob[16] - ob[0]) / (s_kn[sj + 1] - s_kn[sj]);
      }
      lbar();
      // L1 (streamed): row o2, quarter q over 32 y-ins
      {
        uint4 a0 = wvp[0], a1 = wvp[1024], a2 = wvp[2048], a3 = wvp[3072];
        const float* yb = s_yin + q * 32;
        float acc = 0.f;
        acc = qmac2(a0.x, yb[0],  yb[1],  acc);
        acc = qmac2(a0.y, yb[2],  yb[3],  acc);
        acc = qmac2(a0.z, yb[4],  yb[5],  acc);
        acc = qmac2(a0.w, yb[6],  yb[7],  acc);
        acc = qmac2(a1.x, yb[8],  yb[9],  acc);
        acc = qmac2(a1.y, yb[10], yb[11], acc);
        acc = qmac2(a1.z, yb[12], yb[13], acc);
        acc = qmac2(a1.w, yb[14], yb[15], acc);
        acc = qmac2(a2.x, yb[16], yb[17], acc);
        acc = qmac2(a2.y, yb[18], yb[19], acc);
        acc = qmac2(a2.z, yb[20], yb[21], acc);
        acc = qmac2(a2.w, yb[22], yb[23], acc);
        acc = qmac2(a3.x, yb[24], yb[25], acc);
        acc = qmac2(a3.y, yb[26], yb[27], acc);
        acc = qmac2(a3.z, yb[28], yb[29], acc);
        acc = qmac2(a3.w, yb[30], yb[31], acc);
        acc += __shfl_xor(acc, 1);
        acc += __shfl_xor(acc, 2);
        if (q == 0) s_h1[o2] = sp(acc * sc_wv + bl1);
      }
      lbar();
      // m0 (LDS) + PREFETCH m1's 8 chunks (in flight across barrier)
      uint4 pm[8];
#pragma unroll
      for (int c = 0; c < 8; ++c) pm[c] = wm1p[c * 1024];
      {
        float acc = 0.f;
#pragma unroll
        for (int k = 0; k < 8; ++k) {
          uint4 w = *(const uint4*)(&s_m0[o2][(q * 32 + 4 * k) ^ m0sw]);
          float4 ha = *(const float4*)(s_h1 + q * 64 + 8 * k);
          float4 hb = *(const float4*)(s_h1 + q * 64 + 8 * k + 4);
          acc = qmac2(w.x, ha.x, ha.y, acc);
          acc = qmac2(w.y, ha.z, ha.w, acc);
          acc = qmac2(w.z, hb.x, hb.y, acc);
          acc = qmac2(w.w, hb.z, hb.w, acc);
        }
        acc += __shfl_xor(acc, 1);
        acc += __shfl_xor(acc, 2);
        if (q == 0) s_h2[o2] = sp(acc * sc_m0 + bm0);
      }
      lbar();
      // m1 (consume pm) + PREFETCH L4's first 8 chunks
      uint4 pl[8];
#pragma unroll
      for (int c = 0; c < 8; ++c) pl[c] = wl4p[c * 1024];
      {
        float acc = 0.f;
#pragma unroll
        for (int c = 0; c < 8; ++c) {
          float4 ha = *(const float4*)(s_h2 + q * 64 + 8 * c);
          float4 hb = *(const float4*)(s_h2 + q * 64 + 8 * c + 4);
          acc = qmac2(pm[c].x, ha.x, ha.y, acc);
          acc = qmac2(pm[c].y, ha.z, ha.w, acc);
          acc = qmac2(pm[c].z, hb.x, hb.y, acc);
          acc = qmac2(pm[c].w, hb.z, hb.w, acc);
        }
        acc += __shfl_xor(acc, 1);
        acc += __shfl_xor(acc, 2);
        if (q == 0) s_h3[o2] = sp(acc * sc_m1 + bm1);
      }
      lbar();
      // L4: rows 2t (z0, chunks 0-31) and 2t+1 (z1, chunks 32-63)
      {
        float z0 = 0.f, z1 = 0.f;
#pragma unroll
        for (int cc = 0; cc < 8; ++cc) {
          float4 ha = *(const float4*)(s_h3 + 8 * cc);
          float4 hb = *(const float4*)(s_h3 + 8 * cc + 4);
          uint4 w0 = pl[cc];
          uint4 w1 = wl4p[(size_t)(32 + cc) * 1024];
          z0 = qmac2(w0.x, ha.x, ha.y, z0); z0 = qmac2(w0.y, ha.z, ha.w, z0);
          z0 = qmac2(w0.z, hb.x, hb.y, z0); z0 = qmac2(w0.w, hb.z, hb.w, z0);
          z1 = qmac2(w1.x, ha.x, ha.y, z1); z1 = qmac2(w1.y, ha.z, ha.w, z1);
          z1 = qmac2(w1.z, hb.x, hb.y, z1); z1 = qmac2(w1.w, hb.z, hb.w, z1);
        }
#pragma unroll 8
        for (int cc = 8; cc < 32; ++cc) {
          float4 ha = *(const float4*)(s_h3 + 8 * cc);
          float4 hb = *(const float4*)(s_h3 + 8 * cc + 4);
          uint4 w0 = wl4p[(size_t)cc * 1024];
          uint4 w1 = wl4p[(size_t)(32 + cc) * 1024];
          z0 = qmac2(w0.x, ha.x, ha.y, z0); z0 = qmac2(w0.y, ha.z, ha.w, z0);
          z0 = qmac2(w0.z, hb.x, hb.y, z0); z0 = qmac2(w0.w, hb.z, hb.w, z0);
          z1 = qmac2(w1.x, ha.x, ha.y, z1); z1 = qmac2(w1.y, ha.z, ha.w, z1);
          z1 = qmac2(w1.z, hb.x, hb.y, z1); z1 = qmac2(w1.w, hb.z, hb.w, z1);
        }
        const int d0 = 2 * dq;
        float kv;
        kv = tanhf(fmaf(z0, scl4.x, vb2.x)) * s_dx[d0];
        kv = fmaf(tanhf(fmaf(z1, scl4.y, vb2.y)), s_dx[d0 + 1], kv);
        kv += __shfl_xor(kv, 1);
        kv += __shfl_xor(kv, 2);
        kv += __shfl_xor(kv, 4);
        if (owner) {
          kreg = kv;
          if (e == 0) kacc = kv;
          else kacc = fmaf((e == 3) ? 1.f : 2.f, kv, kacc);
          if (e == 3) {
            yreg = fmaf(dt * (1.f / 6.f), kacc, yreg);
            out[(size_t)b * 8192 + (size_t)(l + 1) * 128 + hq] =
                (tl1 <= tm) ? yreg : -99.f;
          }
        }
      }
      lbar();   // protect s_yin/s_dx/s_h3 before next phase-0
    }
  }
}

extern "C" void kernel_launch(void* const* d_in, const int* in_sizes, int n_in,
                              void* d_out, int out_size, void* d_ws, size_t ws_size,
                              hipStream_t stream) {
  const float* ts     = (const float*)d_in[0];
  const float* tsi    = (const float*)d_in[1];
  const float* obs    = (const float*)d_in[2];
  const float* tmaxp  = (const float*)d_in[3];
  const float* i_win  = (const float*)d_in[4];
  const float* i_bin  = (const float*)d_in[5];
  const float* i_wmid = (const float*)d_in[6];
  const float* i_bmid = (const float*)d_in[7];
  const float* i_wout = (const float*)d_in[8];
  const float* i_bout = (const float*)d_in[9];
  const float* v_win  = (const float*)d_in[10];
  const float* v_bin  = (const float*)d_in[11];
  const float* v_wmid = (const float*)d_in[12];
  const float* v_bmid = (const float*)d_in[13];
  const float* v_wout = (const float*)d_in[14];
  const float* v_bout = (const float*)d_in[15];

  unsigned char* wsb = (unsigned char*)d_ws;   // needs 1,387,520 B

  prep_kernel<<<dim3(2816), dim3(64), 0, stream>>>(v_win, v_wmid, v_wout, wsb);
  ncde_kernel<<<dim3(NB), dim3(NTHR), 0, stream>>>(
      ts, tsi, obs, tmaxp,
      i_win, i_bin, i_wmid, i_bmid, i_wout, i_bout,
      v_bin, v_bmid, v_bout,
      wsb, (float*)d_out);
}

// Round 15
// 4872.718 us; speedup vs baseline: 1.3619x; 1.3619x over previous
//
#include <hip/hip_runtime.h>
#include <stdint.h>

// Online Neural CDE — R15: R13's zero-sync kernel (proven: 4306us, absmax
// 20.8) + overlap levers at safe occupancy. 1 batch = 1 block = 1 CU
// (128 blocks x 512 threads, ~190 VGPR -> 2 waves/SIMD, no spills; R14's
// 1024-thread variant capped VGPRs at 64 and spilled to scratch: FETCH 8.5MB
// -> 2.4GB). int16 weights (per-row scales) + fp32 activations/state.
// NEW vs R13: (1) in-loop barriers are lgkm-only so the L2 weight stream
// stays in flight across phases (__syncthreads' vmcnt(0) drain serialized
// stream vs compute); (2) register prefetch of m1's first chunks during the
// LDS-only m0 phase and L4's first chunks during m1.

#define NB   128
#define NTHR 512

// d_ws byte layout (total 1,387,520 B)
#define SC_OFF   0u        // 2816 f32: wv[0..255] m1[256..511] l4[512..2559] m0[2560..2815]
#define WV_OFF   11264u
#define WM1_OFF  76800u
#define WL4_OFF  207872u
#define WM0_OFF  1256448u

static __device__ __forceinline__ float qmac2(uint32_t q, float h0, float h1, float acc) {
  acc = fmaf((float)(short)(q & 0xffffu), h0, acc);
  return fmaf((float)(short)(q >> 16), h1, acc);
}

// precise softplus: max(x,0) + log1p(exp(-|x|))
static __device__ __forceinline__ float sp(float x) {
  return fmaxf(x, 0.f) + log1pf(expf(-fabsf(x)));
}

// LDS-only barrier: orders all LDS traffic, leaves global loads in flight.
static __device__ __forceinline__ void lbar() {
  asm volatile("s_waitcnt lgkmcnt(0)\n\ts_barrier" ::: "memory");
}

// np.searchsorted(kn, t, 'right') - 1, clipped to [0, 62]; 64 knots.
static __device__ __forceinline__ int seg_idx(const float* kn, float t) {
  int lo = 0, hi = 64;
  while (lo < hi) { int mid = (lo + hi) >> 1; if (kn[mid] <= t) lo = mid + 1; else hi = mid; }
  int jj = lo - 1;
  return jj < 0 ? 0 : (jj > 62 ? 62 : jj);
}

// ---- prep: per-row int16 quantization into chunk-tiled streaming layouts ----
// rows: [0,256) v_win | [256,512) v_wmid[1] | [512,2560) v_wout | [2560,2816) v_wmid[0]
__global__ void prep_kernel(const float* __restrict__ v_win,
                            const float* __restrict__ v_wmid,
                            const float* __restrict__ v_wout,
                            unsigned char* __restrict__ wsb) {
  float* scales = (float*)(wsb + SC_OFF);
  short* wv  = (short*)(wsb + WV_OFF);
  short* wm1 = (short*)(wsb + WM1_OFF);
  short* wl4 = (short*)(wsb + WL4_OFF);
  short* wm0 = (short*)(wsb + WM0_OFF);
  const int r = blockIdx.x, lane = threadIdx.x;
  const float* src;
  int n, si;
  if (r < 256)       { src = v_win  + (size_t)r * 128;                n = 128; si = r; }
  else if (r < 512)  { src = v_wmid + 65536 + (size_t)(r - 256) * 256; n = 256; si = r; }
  else if (r < 2560) { src = v_wout + (size_t)(r - 512) * 256;         n = 256; si = r; }
  else               { src = v_wmid + (size_t)(r - 2560) * 256;        n = 256; si = r; }
  float m = 0.f;
  for (int i = lane; i < n; i += 64) m = fmaxf(m, fabsf(src[i]));
#pragma unroll
  for (int off = 32; off; off >>= 1) m = fmaxf(m, __shfl_xor(m, off));
  const float inv = (m > 0.f) ? 32767.f / m : 0.f;
  if (lane == 0) scales[si] = (m > 0.f) ? m / 32767.f : 1.f;
  for (int i = lane; i < n; i += 64) {
    short q = (short)rintf(src[i] * inv);
    if (r < 256) {
      int hf = i >> 6, c = (i & 63) >> 3, e = i & 7;
      wv[c * 4096 + (2 * r + hf) * 8 + e] = q;
    } else if (r < 512) {
      int row = r - 256, hf = i >> 7, c = (i & 127) >> 3, e = i & 7;
      wm1[c * 4096 + (2 * row + hf) * 8 + e] = q;
    } else if (r < 2560) {
      int row = r - 512;
      wl4[((row & 3) * 32 + (i >> 3)) * 4096 + (row >> 2) * 8 + (i & 7)] = q;
    } else {
      int row = r - 2560;
      wm0[(size_t)row * 256 + i] = q;
    }
  }
}

__global__ void __launch_bounds__(NTHR)
ncde_kernel(const float* __restrict__ ts, const float* __restrict__ tsi,
            const float* __restrict__ obs, const float* __restrict__ tmax,
            const float* __restrict__ i_win, const float* __restrict__ i_bin,
            const float* __restrict__ i_wmid, const float* __restrict__ i_bmid,
            const float* __restrict__ i_wout, const float* __restrict__ i_bout,
            const float* __restrict__ v_wmid, const float* __restrict__ v_bin,
            const float* __restrict__ v_bmid, const float* __restrict__ v_bout,
            const unsigned char* __restrict__ wsb, float* __restrict__ out) {
  __shared__ __align__(16) uint32_t s_m0[256][132];   // int16-pair m0, swizzled
  __shared__ __align__(16) float s_yin[132];
  __shared__ __align__(16) float s_h1[256];
  __shared__ __align__(16) float s_h2[256];
  __shared__ __align__(16) float s_h3[256];
  __shared__ __align__(16) float s_ts[64];
  __shared__ __align__(16) float s_kn[64];
  __shared__ float s_dx[16];
  __shared__ float s_x0[16];
  __shared__ unsigned char s_sj[128];

  const int t = threadIdx.x;
  const int b = blockIdx.x;
  const int o = t >> 1, half = t & 1;
  const bool owner = (t & 3) == 0;
  const int h = t >> 2;

  const float* scales = (const float*)(wsb + SC_OFF);
  const uint4* wvp  = ((const uint4*)(wsb + WV_OFF)) + t;
  const uint4* wm1p = ((const uint4*)(wsb + WM1_OFF)) + t;
  const uint4* wl4p = ((const uint4*)(wsb + WL4_OFF)) + t;

  if (t < 64) { s_ts[t] = ts[b * 64 + t]; s_kn[t] = tsi[b * 64 + t]; }
  const float tm = tmax[b];
  const float bl1 = v_bin[o];
  const float bm0 = v_bmid[o];
  const float bm1 = v_bmid[256 + o];
  const float4 vb4 = *(const float4*)(v_bout + 4 * t);
  const float sc_wv = scales[o];
  const float sc_m1 = scales[256 + o];
  const float sc_m0 = scales[2560 + o];
  const float4 sc_l4 = *(const float4*)(scales + 512 + 4 * t);
  __syncthreads();

  // m0 -> LDS (coalesced u32 copy, quartet-breaking swizzle on cols)
  {
    const uint32_t* wm0u = (const uint32_t*)(wsb + WM0_OFF);
    for (int idx = t; idx < 32768; idx += NTHR) {
      int row = idx >> 7, k = idx & 127;
      s_m0[row][k ^ (((row >> 3) & 3) << 2)] = wm0u[idx];
    }
  }
  if (t < 127) {
    int li = t >> 1;
    float te = (t & 1) ? fmaf(0.5f, s_ts[li + 1] - s_ts[li], s_ts[li]) : s_ts[li];
    s_sj[t] = (unsigned char)seg_idx(s_kn, te);
  }
  __syncthreads();

  // ---------------- init MLP: y0 = MLP_i(x0) (one-time, fp32 weights) ------
  if (t < 16) {
    float t0 = s_ts[0];
    int sj = s_sj[0];
    float k0 = s_kn[sj], k1 = s_kn[sj + 1];
    float fr = (t0 - k0) / (k1 - k0);
    const float* ob = obs + ((size_t)b * 64 + sj) * 16 + t;
    s_x0[t] = fmaf(fr, ob[16] - ob[0], ob[0]);
  }
  __syncthreads();
  if (t < 256) {                       // L1i: o=t, 16 ins
    float acc = i_bin[t];
    const float* wr = i_win + (size_t)t * 16;
#pragma unroll
    for (int i = 0; i < 16; ++i) acc = fmaf(wr[i], s_x0[i], acc);
    s_h1[t] = sp(acc);
  }
  __syncthreads();
  {                                    // m0i: o, half over 128 ins
    float acc = 0.f;
    const float4* wq = (const float4*)(i_wmid + (size_t)o * 256 + half * 128);
    const float4* hp = (const float4*)(s_h1 + half * 128);
#pragma unroll
    for (int i = 0; i < 32; ++i) {
      float4 w = wq[i]; float4 hh = hp[i];
      acc = fmaf(w.x, hh.x, acc); acc = fmaf(w.y, hh.y, acc);
      acc = fmaf(w.z, hh.z, acc); acc = fmaf(w.w, hh.w, acc);
    }
    acc += __shfl_xor(acc, 1);
    if (!half) s_h2[o] = sp(acc + i_bmid[o]);
  }
  __syncthreads();
  {                                    // m1i
    float acc = 0.f;
    const float4* wq = (const float4*)(i_wmid + 65536 + (size_t)o * 256 + half * 128);
    const float4* hp = (const float4*)(s_h2 + half * 128);
#pragma unroll
    for (int i = 0; i < 32; ++i) {
      float4 w = wq[i]; float4 hh = hp[i];
      acc = fmaf(w.x, hh.x, acc); acc = fmaf(w.y, hh.y, acc);
      acc = fmaf(w.z, hh.z, acc); acc = fmaf(w.w, hh.w, acc);
    }
    acc += __shfl_xor(acc, 1);
    if (!half) s_h3[o] = sp(acc + i_bmid[256 + o]);
  }
  __syncthreads();
  float yreg = 0.f, kreg = 0.f, kacc = 0.f;
  {                                    // L4i: row h=t>>2, quarter q=t&3
    float acc = 0.f;
    const float4* wq = (const float4*)(i_wout + (size_t)h * 256 + (t & 3) * 64);
    const float4* hp = (const float4*)(s_h3 + (t & 3) * 64);
#pragma unroll
    for (int i = 0; i < 16; ++i) {
      float4 w = wq[i]; float4 hh = hp[i];
      acc = fmaf(w.x, hh.x, acc); acc = fmaf(w.y, hh.y, acc);
      acc = fmaf(w.z, hh.z, acc); acc = fmaf(w.w, hh.w, acc);
    }
    acc += __shfl_xor(acc, 1);
    acc += __shfl_xor(acc, 2);
    if (owner) {
      yreg = acc + i_bout[h];
      out[(size_t)b * 8192 + h] = (s_ts[0] <= tm) ? yreg : -99.f;
    }
  }
  __syncthreads();

  // ---------------- RK4 over 63 intervals, fully block-local ---------------
#pragma unroll 1
  for (int l = 0; l < 63; ++l) {
    const float tl1 = s_ts[l + 1];
    const float dt = tl1 - s_ts[l];
#pragma unroll 1
    for (int e = 0; e < 4; ++e) {
      // phase 0: owners publish y_in; 16 lanes compute dx(t_e)
      if (owner) {
        float ce = (e == 0) ? 0.f : ((e == 3) ? 1.f : 0.5f);
        s_yin[h] = fmaf(ce * dt, kreg, yreg);
      }
      if (t < 16) {
        int ti = 2 * l + ((e == 0) ? 0 : ((e == 3) ? 2 : 1));
        int sj = s_sj[ti];
        const float* ob = obs + ((size_t)b * 64 + sj) * 16 + t;
        s_dx[t] = (ob[16] - ob[0]) / (s_kn[sj + 1] - s_kn[sj]);
      }
      lbar();
      // L1 (streamed int16): row o, half over 64 y-ins
      {
        float acc = 0.f;
#pragma unroll
        for (int c = 0; c < 8; ++c) {
          uint4 w = wvp[c * 512];
          float4 ya = *(const float4*)(s_yin + half * 64 + 8 * c);
          float4 yb = *(const float4*)(s_yin + half * 64 + 8 * c + 4);
          acc = qmac2(w.x, ya.x, ya.y, acc);
          acc = qmac2(w.y, ya.z, ya.w, acc);
          acc = qmac2(w.z, yb.x, yb.y, acc);
          acc = qmac2(w.w, yb.z, yb.w, acc);
        }
        acc += __shfl_xor(acc, 1);
        if (!half) s_h1[o] = sp(acc * sc_wv + bl1);
      }
      lbar();
      // m0 (LDS int16) + PREFETCH m1's first 8 chunks (fly across barrier)
      uint4 pm[8];
#pragma unroll
      for (int c = 0; c < 8; ++c) pm[c] = wm1p[c * 512];
      {
        float acc = 0.f;
        const int swz = ((o >> 3) & 3) << 2;
        const uint32_t* wr = &s_m0[o][0];
#pragma unroll
        for (int k = 0; k < 16; ++k) {
          uint4 w = *(const uint4*)(wr + (((half * 64 + 4 * k)) ^ swz));
          float4 ha = *(const float4*)(s_h1 + half * 128 + 8 * k);
          float4 hb = *(const float4*)(s_h1 + half * 128 + 8 * k + 4);
          acc = qmac2(w.x, ha.x, ha.y, acc);
          acc = qmac2(w.y, ha.z, ha.w, acc);
          acc = qmac2(w.z, hb.x, hb.y, acc);
          acc = qmac2(w.w, hb.z, hb.w, acc);
        }
        acc += __shfl_xor(acc, 1);
        if (!half) s_h2[o] = sp(acc * sc_m0 + bm0);
      }
      lbar();
      // m1 (consume pm, stream rest) + PREFETCH L4's first 8 chunks
      uint4 pl[8];
#pragma unroll
      for (int c = 0; c < 8; ++c) pl[c] = wl4p[c * 512];
      {
        float acc = 0.f;
#pragma unroll
        for (int c = 0; c < 8; ++c) {
          float4 ha = *(const float4*)(s_h2 + half * 128 + 8 * c);
          float4 hb = *(const float4*)(s_h2 + half * 128 + 8 * c + 4);
          acc = qmac2(pm[c].x, ha.x, ha.y, acc);
          acc = qmac2(pm[c].y, ha.z, ha.w, acc);
          acc = qmac2(pm[c].z, hb.x, hb.y, acc);
          acc = qmac2(pm[c].w, hb.z, hb.w, acc);
        }
#pragma unroll
        for (int c = 8; c < 16; ++c) {
          uint4 w = wm1p[c * 512];
          float4 ha = *(const float4*)(s_h2 + half * 128 + 8 * c);
          float4 hb = *(const float4*)(s_h2 + half * 128 + 8 * c + 4);
          acc = qmac2(w.x, ha.x, ha.y, acc);
          acc = qmac2(w.y, ha.z, ha.w, acc);
          acc = qmac2(w.z, hb.x, hb.y, acc);
          acc = qmac2(w.w, hb.z, hb.w, acc);
        }
        acc += __shfl_xor(acc, 1);
        if (!half) s_h3[o] = sp(acc * sc_m1 + bm1);
      }
      lbar();
      // L4 (streamed int16, 1MB): rows 4t..4t+3; pl covers row0 chunks 0-7
      {
        float z0 = 0.f, z1 = 0.f, z2 = 0.f, z3 = 0.f;
        const uint4* p1 = wl4p + 32 * 512;
        const uint4* p2 = wl4p + 64 * 512;
        const uint4* p3 = wl4p + 96 * 512;
#pragma unroll 4
        for (int cc = 0; cc < 8; ++cc) {
          float4 ha = *(const float4*)(s_h3 + 8 * cc);
          float4 hb = *(const float4*)(s_h3 + 8 * cc + 4);
          uint4 w0 = pl[cc];
          uint4 w1 = p1[cc * 512];
          uint4 w2 = p2[cc * 512];
          uint4 w3 = p3[cc * 512];
          z0 = qmac2(w0.x, ha.x, ha.y, z0); z0 = qmac2(w0.y, ha.z, ha.w, z0);
          z0 = qmac2(w0.z, hb.x, hb.y, z0); z0 = qmac2(w0.w, hb.z, hb.w, z0);
          z1 = qmac2(w1.x, ha.x, ha.y, z1); z1 = qmac2(w1.y, ha.z, ha.w, z1);
          z1 = qmac2(w1.z, hb.x, hb.y, z1); z1 = qmac2(w1.w, hb.z, hb.w, z1);
          z2 = qmac2(w2.x, ha.x, ha.y, z2); z2 = qmac2(w2.y, ha.z, ha.w, z2);
          z2 = qmac2(w2.z, hb.x, hb.y, z2); z2 = qmac2(w2.w, hb.z, hb.w, z2);
          z3 = qmac2(w3.x, ha.x, ha.y, z3); z3 = qmac2(w3.y, ha.z, ha.w, z3);
          z3 = qmac2(w3.z, hb.x, hb.y, z3); z3 = qmac2(w3.w, hb.z, hb.w, z3);
        }
#pragma unroll 4
        for (int cc = 8; cc < 32; ++cc) {
          float4 ha = *(const float4*)(s_h3 + 8 * cc);
          float4 hb = *(const float4*)(s_h3 + 8 * cc + 4);
          uint4 w0 = wl4p[cc * 512];
          uint4 w1 = p1[cc * 512];
          uint4 w2 = p2[cc * 512];
          uint4 w3 = p3[cc * 512];
          z0 = qmac2(w0.x, ha.x, ha.y, z0); z0 = qmac2(w0.y, ha.z, ha.w, z0);
          z0 = qmac2(w0.z, hb.x, hb.y, z0); z0 = qmac2(w0.w, hb.z, hb.w, z0);
          z1 = qmac2(w1.x, ha.x, ha.y, z1); z1 = qmac2(w1.y, ha.z, ha.w, z1);
          z1 = qmac2(w1.z, hb.x, hb.y, z1); z1 = qmac2(w1.w, hb.z, hb.w, z1);
          z2 = qmac2(w2.x, ha.x, ha.y, z2); z2 = qmac2(w2.y, ha.z, ha.w, z2);
          z2 = qmac2(w2.z, hb.x, hb.y, z2); z2 = qmac2(w2.w, hb.z, hb.w, z2);
          z3 = qmac2(w3.x, ha.x, ha.y, z3); z3 = qmac2(w3.y, ha.z, ha.w, z3);
          z3 = qmac2(w3.z, hb.x, hb.y, z3); z3 = qmac2(w3.w, hb.z, hb.w, z3);
        }
        const int d0 = 4 * (t & 3);
        float kv = 0.f;
        kv = fmaf(tanhf(fmaf(z0, sc_l4.x, vb4.x)), s_dx[d0 + 0], kv);
        kv = fmaf(tanhf(fmaf(z1, sc_l4.y, vb4.y)), s_dx[d0 + 1], kv);
        kv = fmaf(tanhf(fmaf(z2, sc_l4.z, vb4.z)), s_dx[d0 + 2], kv);
        kv = fmaf(tanhf(fmaf(z3, sc_l4.w, vb4.w)), s_dx[d0 + 3], kv);
        kv += __shfl_xor(kv, 1);
        kv += __shfl_xor(kv, 2);
        if (owner) {
          kreg = kv;
          if (e == 0) kacc = kv;
          else kacc = fmaf((e == 3) ? 1.f : 2.f, kv, kacc);
          if (e == 3) {
            yreg = fmaf(dt * (1.f / 6.f), kacc, yreg);
            out[(size_t)b * 8192 + (size_t)(l + 1) * 128 + h] =
                (tl1 <= tm) ? yreg : -99.f;
          }
        }
      }
      lbar();   // protect s_yin/s_dx/s_h3 before next phase-0
    }
  }
}

extern "C" void kernel_launch(void* const* d_in, const int* in_sizes, int n_in,
                              void* d_out, int out_size, void* d_ws, size_t ws_size,
                              hipStream_t stream) {
  const float* ts     = (const float*)d_in[0];
  const float* tsi    = (const float*)d_in[1];
  const float* obs    = (const float*)d_in[2];
  const float* tmaxp  = (const float*)d_in[3];
  const float* i_win  = (const float*)d_in[4];
  const float* i_bin  = (const float*)d_in[5];
  const float* i_wmid = (const float*)d_in[6];
  const float* i_bmid = (const float*)d_in[7];
  const float* i_wout = (const float*)d_in[8];
  const float* i_bout = (const float*)d_in[9];
  const float* v_win  = (const float*)d_in[10];
  const float* v_bin  = (const float*)d_in[11];
  const float* v_wmid = (const float*)d_in[12];
  const float* v_bmid = (const float*)d_in[13];
  const float* v_wout = (const float*)d_in[14];
  const float* v_bout = (const float*)d_in[15];

  unsigned char* wsb = (unsigned char*)d_ws;   // needs 1,387,520 B

  prep_kernel<<<dim3(2816), dim3(64), 0, stream>>>(v_win, v_wmid, v_wout, wsb);
  ncde_kernel<<<dim3(NB), dim3(NTHR), 0, stream>>>(
      ts, tsi, obs, tmaxp,
      i_win, i_bin, i_wmid, i_bmid, i_wout, i_bout,
      v_wmid, v_bin, v_bmid, v_bout,
      wsb, (float*)d_out);
}

// Round 16
// 3647.725 us; speedup vs baseline: 1.8192x; 1.3358x over previous
//
#include <hip/hip_runtime.h>
#include <stdint.h>

// Online Neural CDE — R16: R13's zero-sync kernel (4306us, absmax 20.8)
// with EXACTLY ONE change: in-loop barriers are lgkm-only (s_waitcnt
// lgkmcnt(0); s_barrier) instead of __syncthreads, so the L2 weight stream
// stays in flight across phase boundaries. R15 entangled this lever with
// register prefetch, which spilled (WRITE_SIZE 4MB -> 1.38GB) and masked it.
// 1 batch = 1 block = 1 CU (128 blocks x 512 threads). int16 weights
// (per-row scales, chunk-tiled in d_ws) + fp32 activations/state.
// m0 LDS-resident; v_win/v_wmid[1]/v_wout streamed from XCD L2 every eval.

#define NB   128
#define NTHR 512

// d_ws byte layout (total 1,387,520 B)
#define SC_OFF   0u        // 2816 f32: wv[0..255] m1[256..511] l4[512..2559] m0[2560..2815]
#define WV_OFF   11264u
#define WM1_OFF  76800u
#define WL4_OFF  207872u
#define WM0_OFF  1256448u

static __device__ __forceinline__ float qmac2(uint32_t q, float h0, float h1, float acc) {
  acc = fmaf((float)(short)(q & 0xffffu), h0, acc);
  return fmaf((float)(short)(q >> 16), h1, acc);
}

// precise softplus: max(x,0) + log1p(exp(-|x|))
static __device__ __forceinline__ float sp(float x) {
  return fmaxf(x, 0.f) + log1pf(expf(-fabsf(x)));
}

// LDS-only barrier: orders all LDS traffic, leaves global loads in flight.
static __device__ __forceinline__ void lbar() {
  asm volatile("s_waitcnt lgkmcnt(0)\n\ts_barrier" ::: "memory");
}

// np.searchsorted(kn, t, 'right') - 1, clipped to [0, 62]; 64 knots.
static __device__ __forceinline__ int seg_idx(const float* kn, float t) {
  int lo = 0, hi = 64;
  while (lo < hi) { int mid = (lo + hi) >> 1; if (kn[mid] <= t) lo = mid + 1; else hi = mid; }
  int jj = lo - 1;
  return jj < 0 ? 0 : (jj > 62 ? 62 : jj);
}

// ---- prep: per-row int16 quantization into chunk-tiled streaming layouts ----
// rows: [0,256) v_win | [256,512) v_wmid[1] | [512,2560) v_wout | [2560,2816) v_wmid[0]
__global__ void prep_kernel(const float* __restrict__ v_win,
                            const float* __restrict__ v_wmid,
                            const float* __restrict__ v_wout,
                            unsigned char* __restrict__ wsb) {
  float* scales = (float*)(wsb + SC_OFF);
  short* wv  = (short*)(wsb + WV_OFF);
  short* wm1 = (short*)(wsb + WM1_OFF);
  short* wl4 = (short*)(wsb + WL4_OFF);
  short* wm0 = (short*)(wsb + WM0_OFF);
  const int r = blockIdx.x, lane = threadIdx.x;
  const float* src;
  int n, si;
  if (r < 256)       { src = v_win  + (size_t)r * 128;                n = 128; si = r; }
  else if (r < 512)  { src = v_wmid + 65536 + (size_t)(r - 256) * 256; n = 256; si = r; }
  else if (r < 2560) { src = v_wout + (size_t)(r - 512) * 256;         n = 256; si = r; }
  else               { src = v_wmid + (size_t)(r - 2560) * 256;        n = 256; si = r; }
  float m = 0.f;
  for (int i = lane; i < n; i += 64) m = fmaxf(m, fabsf(src[i]));
#pragma unroll
  for (int off = 32; off; off >>= 1) m = fmaxf(m, __shfl_xor(m, off));
  const float inv = (m > 0.f) ? 32767.f / m : 0.f;
  if (lane == 0) scales[si] = (m > 0.f) ? m / 32767.f : 1.f;
  for (int i = lane; i < n; i += 64) {
    short q = (short)rintf(src[i] * inv);
    if (r < 256) {
      int hf = i >> 6, c = (i & 63) >> 3, e = i & 7;
      wv[c * 4096 + (2 * r + hf) * 8 + e] = q;
    } else if (r < 512) {
      int row = r - 256, hf = i >> 7, c = (i & 127) >> 3, e = i & 7;
      wm1[c * 4096 + (2 * row + hf) * 8 + e] = q;
    } else if (r < 2560) {
      int row = r - 512;
      wl4[((row & 3) * 32 + (i >> 3)) * 4096 + (row >> 2) * 8 + (i & 7)] = q;
    } else {
      int row = r - 2560;
      wm0[(size_t)row * 256 + i] = q;
    }
  }
}

__global__ void __launch_bounds__(NTHR)
ncde_kernel(const float* __restrict__ ts, const float* __restrict__ tsi,
            const float* __restrict__ obs, const float* __restrict__ tmax,
            const float* __restrict__ i_win, const float* __restrict__ i_bin,
            const float* __restrict__ i_wmid, const float* __restrict__ i_bmid,
            const float* __restrict__ i_wout, const float* __restrict__ i_bout,
            const float* __restrict__ v_wmid, const float* __restrict__ v_bin,
            const float* __restrict__ v_bmid, const float* __restrict__ v_bout,
            const unsigned char* __restrict__ wsb, float* __restrict__ out) {
  __shared__ __align__(16) uint32_t s_m0[256][132];   // int16-pair m0, swizzled
  __shared__ __align__(16) float s_yin[132];
  __shared__ __align__(16) float s_h1[256];
  __shared__ __align__(16) float s_h2[256];
  __shared__ __align__(16) float s_h3[256];
  __shared__ __align__(16) float s_ts[64];
  __shared__ __align__(16) float s_kn[64];
  __shared__ float s_dx[16];
  __shared__ float s_x0[16];
  __shared__ unsigned char s_sj[128];

  const int t = threadIdx.x;
  const int b = blockIdx.x;
  const int o = t >> 1, half = t & 1;
  const bool owner = (t & 3) == 0;
  const int h = t >> 2;

  const float* scales = (const float*)(wsb + SC_OFF);
  const uint4* wvp  = ((const uint4*)(wsb + WV_OFF)) + t;
  const uint4* wm1p = ((const uint4*)(wsb + WM1_OFF)) + t;
  const uint4* wl4p = ((const uint4*)(wsb + WL4_OFF)) + t;

  if (t < 64) { s_ts[t] = ts[b * 64 + t]; s_kn[t] = tsi[b * 64 + t]; }
  const float tm = tmax[b];
  const float bl1 = v_bin[o];
  const float bm0 = v_bmid[o];
  const float bm1 = v_bmid[256 + o];
  const float4 vb4 = *(const float4*)(v_bout + 4 * t);
  const float sc_wv = scales[o];
  const float sc_m1 = scales[256 + o];
  const float sc_m0 = scales[2560 + o];
  const float4 sc_l4 = *(const float4*)(scales + 512 + 4 * t);
  __syncthreads();

  // m0 -> LDS (coalesced u32 copy, quartet-breaking swizzle on cols)
  {
    const uint32_t* wm0u = (const uint32_t*)(wsb + WM0_OFF);
    for (int idx = t; idx < 32768; idx += NTHR) {
      int row = idx >> 7, k = idx & 127;
      s_m0[row][k ^ (((row >> 3) & 3) << 2)] = wm0u[idx];
    }
  }
  if (t < 127) {
    int li = t >> 1;
    float te = (t & 1) ? fmaf(0.5f, s_ts[li + 1] - s_ts[li], s_ts[li]) : s_ts[li];
    s_sj[t] = (unsigned char)seg_idx(s_kn, te);
  }
  __syncthreads();

  // ---------------- init MLP: y0 = MLP_i(x0) (one-time, fp32 weights) ------
  if (t < 16) {
    float t0 = s_ts[0];
    int sj = s_sj[0];
    float k0 = s_kn[sj], k1 = s_kn[sj + 1];
    float fr = (t0 - k0) / (k1 - k0);
    const float* ob = obs + ((size_t)b * 64 + sj) * 16 + t;
    s_x0[t] = fmaf(fr, ob[16] - ob[0], ob[0]);
  }
  __syncthreads();
  if (t < 256) {                       // L1i: o=t, 16 ins
    float acc = i_bin[t];
    const float* wr = i_win + (size_t)t * 16;
#pragma unroll
    for (int i = 0; i < 16; ++i) acc = fmaf(wr[i], s_x0[i], acc);
    s_h1[t] = sp(acc);
  }
  __syncthreads();
  {                                    // m0i: o, half over 128 ins
    float acc = 0.f;
    const float4* wq = (const float4*)(i_wmid + (size_t)o * 256 + half * 128);
    const float4* hp = (const float4*)(s_h1 + half * 128);
#pragma unroll
    for (int i = 0; i < 32; ++i) {
      float4 w = wq[i]; float4 hh = hp[i];
      acc = fmaf(w.x, hh.x, acc); acc = fmaf(w.y, hh.y, acc);
      acc = fmaf(w.z, hh.z, acc); acc = fmaf(w.w, hh.w, acc);
    }
    acc += __shfl_xor(acc, 1);
    if (!half) s_h2[o] = sp(acc + i_bmid[o]);
  }
  __syncthreads();
  {                                    // m1i
    float acc = 0.f;
    const float4* wq = (const float4*)(i_wmid + 65536 + (size_t)o * 256 + half * 128);
    const float4* hp = (const float4*)(s_h2 + half * 128);
#pragma unroll
    for (int i = 0; i < 32; ++i) {
      float4 w = wq[i]; float4 hh = hp[i];
      acc = fmaf(w.x, hh.x, acc); acc = fmaf(w.y, hh.y, acc);
      acc = fmaf(w.z, hh.z, acc); acc = fmaf(w.w, hh.w, acc);
    }
    acc += __shfl_xor(acc, 1);
    if (!half) s_h3[o] = sp(acc + i_bmid[256 + o]);
  }
  __syncthreads();
  float yreg = 0.f, kreg = 0.f, kacc = 0.f;
  {                                    // L4i: row h=t>>2, quarter q=t&3
    float acc = 0.f;
    const float4* wq = (const float4*)(i_wout + (size_t)h * 256 + (t & 3) * 64);
    const float4* hp = (const float4*)(s_h3 + (t & 3) * 64);
#pragma unroll
    for (int i = 0; i < 16; ++i) {
      float4 w = wq[i]; float4 hh = hp[i];
      acc = fmaf(w.x, hh.x, acc); acc = fmaf(w.y, hh.y, acc);
      acc = fmaf(w.z, hh.z, acc); acc = fmaf(w.w, hh.w, acc);
    }
    acc += __shfl_xor(acc, 1);
    acc += __shfl_xor(acc, 2);
    if (owner) {
      yreg = acc + i_bout[h];
      out[(size_t)b * 8192 + h] = (s_ts[0] <= tm) ? yreg : -99.f;
    }
  }
  __syncthreads();

  // ---------------- RK4 over 63 intervals, fully block-local ---------------
#pragma unroll 1
  for (int l = 0; l < 63; ++l) {
    const float tl1 = s_ts[l + 1];
    const float dt = tl1 - s_ts[l];
#pragma unroll 1
    for (int e = 0; e < 4; ++e) {
      // phase 0: owners publish y_in; 16 lanes compute dx(t_e)
      if (owner) {
        float ce = (e == 0) ? 0.f : ((e == 3) ? 1.f : 0.5f);
        s_yin[h] = fmaf(ce * dt, kreg, yreg);
      }
      if (t < 16) {
        int ti = 2 * l + ((e == 0) ? 0 : ((e == 3) ? 2 : 1));
        int sj = s_sj[ti];
        const float* ob = obs + ((size_t)b * 64 + sj) * 16 + t;
        s_dx[t] = (ob[16] - ob[0]) / (s_kn[sj + 1] - s_kn[sj]);
      }
      lbar();
      // L1 (streamed int16): row o, half over 64 y-ins
      {
        float acc = 0.f;
#pragma unroll
        for (int c = 0; c < 8; ++c) {
          uint4 w = wvp[c * 512];
          float4 ya = *(const float4*)(s_yin + half * 64 + 8 * c);
          float4 yb = *(const float4*)(s_yin + half * 64 + 8 * c + 4);
          acc = qmac2(w.x, ya.x, ya.y, acc);
          acc = qmac2(w.y, ya.z, ya.w, acc);
          acc = qmac2(w.z, yb.x, yb.y, acc);
          acc = qmac2(w.w, yb.z, yb.w, acc);
        }
        acc += __shfl_xor(acc, 1);
        if (!half) s_h1[o] = sp(acc * sc_wv + bl1);
      }
      lbar();
      // m0 (LDS int16): row o, half over 128 ins
      {
        float acc = 0.f;
        const int swz = ((o >> 3) & 3) << 2;
        const uint32_t* wr = &s_m0[o][0];
#pragma unroll
        for (int k = 0; k < 16; ++k) {
          uint4 w = *(const uint4*)(wr + (((half * 64 + 4 * k)) ^ swz));
          float4 ha = *(const float4*)(s_h1 + half * 128 + 8 * k);
          float4 hb = *(const float4*)(s_h1 + half * 128 + 8 * k + 4);
          acc = qmac2(w.x, ha.x, ha.y, acc);
          acc = qmac2(w.y, ha.z, ha.w, acc);
          acc = qmac2(w.z, hb.x, hb.y, acc);
          acc = qmac2(w.w, hb.z, hb.w, acc);
        }
        acc += __shfl_xor(acc, 1);
        if (!half) s_h2[o] = sp(acc * sc_m0 + bm0);
      }
      lbar();
      // m1 (streamed int16): row o, half over 128 ins
      {
        float acc = 0.f;
#pragma unroll 4
        for (int c = 0; c < 16; ++c) {
          uint4 w = wm1p[c * 512];
          float4 ha = *(const float4*)(s_h2 + half * 128 + 8 * c);
          float4 hb = *(const float4*)(s_h2 + half * 128 + 8 * c + 4);
          acc = qmac2(w.x, ha.x, ha.y, acc);
          acc = qmac2(w.y, ha.z, ha.w, acc);
          acc = qmac2(w.z, hb.x, hb.y, acc);
          acc = qmac2(w.w, hb.z, hb.w, acc);
        }
        acc += __shfl_xor(acc, 1);
        if (!half) s_h3[o] = sp(acc * sc_m1 + bm1);
      }
      lbar();
      // L4 (streamed int16, 1MB): rows 4t..4t+3, full 256-dot each
      {
        float z0 = 0.f, z1 = 0.f, z2 = 0.f, z3 = 0.f;
#pragma unroll 4
        for (int cc = 0; cc < 32; ++cc) {
          float4 ha = *(const float4*)(s_h3 + 8 * cc);
          float4 hb = *(const float4*)(s_h3 + 8 * cc + 4);
          uint4 w0 = wl4p[(0 * 32 + cc) * 512];
          uint4 w1 = wl4p[(1 * 32 + cc) * 512];
          uint4 w2 = wl4p[(2 * 32 + cc) * 512];
          uint4 w3 = wl4p[(3 * 32 + cc) * 512];
          z0 = qmac2(w0.x, ha.x, ha.y, z0); z0 = qmac2(w0.y, ha.z, ha.w, z0);
          z0 = qmac2(w0.z, hb.x, hb.y, z0); z0 = qmac2(w0.w, hb.z, hb.w, z0);
          z1 = qmac2(w1.x, ha.x, ha.y, z1); z1 = qmac2(w1.y, ha.z, ha.w, z1);
          z1 = qmac2(w1.z, hb.x, hb.y, z1); z1 = qmac2(w1.w, hb.z, hb.w, z1);
          z2 = qmac2(w2.x, ha.x, ha.y, z2); z2 = qmac2(w2.y, ha.z, ha.w, z2);
          z2 = qmac2(w2.z, hb.x, hb.y, z2); z2 = qmac2(w2.w, hb.z, hb.w, z2);
          z3 = qmac2(w3.x, ha.x, ha.y, z3); z3 = qmac2(w3.y, ha.z, ha.w, z3);
          z3 = qmac2(w3.z, hb.x, hb.y, z3); z3 = qmac2(w3.w, hb.z, hb.w, z3);
        }
        const int d0 = 4 * (t & 3);
        float kv = 0.f;
        kv = fmaf(tanhf(fmaf(z0, sc_l4.x, vb4.x)), s_dx[d0 + 0], kv);
        kv = fmaf(tanhf(fmaf(z1, sc_l4.y, vb4.y)), s_dx[d0 + 1], kv);
        kv = fmaf(tanhf(fmaf(z2, sc_l4.z, vb4.z)), s_dx[d0 + 2], kv);
        kv = fmaf(tanhf(fmaf(z3, sc_l4.w, vb4.w)), s_dx[d0 + 3], kv);
        kv += __shfl_xor(kv, 1);
        kv += __shfl_xor(kv, 2);
        if (owner) {
          kreg = kv;
          if (e == 0) kacc = kv;
          else kacc = fmaf((e == 3) ? 1.f : 2.f, kv, kacc);
          if (e == 3) {
            yreg = fmaf(dt * (1.f / 6.f), kacc, yreg);
            out[(size_t)b * 8192 + (size_t)(l + 1) * 128 + h] =
                (tl1 <= tm) ? yreg : -99.f;
          }
        }
      }
      lbar();   // protect s_yin/s_dx/s_h3 before next phase-0
    }
  }
}

extern "C" void kernel_launch(void* const* d_in, const int* in_sizes, int n_in,
                              void* d_out, int out_size, void* d_ws, size_t ws_size,
                              hipStream_t stream) {
  const float* ts     = (const float*)d_in[0];
  const float* tsi    = (const float*)d_in[1];
  const float* obs    = (const float*)d_in[2];
  const float* tmaxp  = (const float*)d_in[3];
  const float* i_win  = (const float*)d_in[4];
  const float* i_bin  = (const float*)d_in[5];
  const float* i_wmid = (const float*)d_in[6];
  const float* i_bmid = (const float*)d_in[7];
  const float* i_wout = (const float*)d_in[8];
  const float* i_bout = (const float*)d_in[9];
  const float* v_win  = (const float*)d_in[10];
  const float* v_bin  = (const float*)d_in[11];
  const float* v_wmid = (const float*)d_in[12];
  const float* v_bmid = (const float*)d_in[13];
  const float* v_wout = (const float*)d_in[14];
  const float* v_bout = (const float*)d_in[15];

  unsigned char* wsb = (unsigned char*)d_ws;   // needs 1,387,520 B

  prep_kernel<<<dim3(2816), dim3(64), 0, stream>>>(v_win, v_wmid, v_wout, wsb);
  ncde_kernel<<<dim3(NB), dim3(NTHR), 0, stream>>>(
      ts, tsi, obs, tmaxp,
      i_win, i_bin, i_wmid, i_bmid, i_wout, i_bout,
      v_wmid, v_bin, v_bmid, v_bout,
      wsb, (float*)d_out);
}

// Round 18
// 2838.095 us; speedup vs baseline: 2.3382x; 1.2853x over previous
//
#include <hip/hip_runtime.h>
#include <stdint.h>

// Online Neural CDE — R18: R17 resubmitted (compile fix only: s_sleep needs a
// constant immediate — use branch with constant args).
// R16 (3648us) + pair-split across 256 CUs. Batch b = blocks b (s=0) and
// b+128 (s=1), 512 threads each. Both blocks run L1/m0/m1 redundantly on
// identical state; L4 (76% of FLOPs, 1MB stream) is split by h-half.
// Per sub-eval each block publishes its 64 k-values as tagged 8B words
// (value+epoch, double-banked); partner polls its 64 words (pairwise,
// lockstep-covered, bounded backoff). Only s=0 writes out.
// int16 weights + fp32 activations/state; lgkm-only in-loop barriers.

#define NB   256
#define NTHR 512

// d_ws byte layout (total 1,649,664 B)
#define SC_OFF   0u        // 2816 f32 scales
#define WV_OFF   11264u    // 64 KB
#define WM1_OFF  76800u    // 128 KB
#define WL4_OFF  207872u   // 1 MB (2 sets x 512 KB)
#define WM0_OFF  1256448u  // 128 KB
#define EX_OFF   1387520u  // 128 batches x 2 sets x 2 banks x 64 u64 = 256 KB

typedef unsigned long long u64t;

static __device__ __forceinline__ u64t ld_coh8(const u64t* p) {
  return __hip_atomic_load(p, __ATOMIC_RELAXED, __HIP_MEMORY_SCOPE_AGENT);
}
static __device__ __forceinline__ void st_coh8(u64t* p, u64t v) {
  __hip_atomic_store(p, v, __ATOMIC_RELAXED, __HIP_MEMORY_SCOPE_AGENT);
}
static __device__ __forceinline__ u64t pack_tf(float f, uint32_t tag) {
  union { float f; uint32_t u; } c; c.f = f;
  return ((u64t)tag << 32) | c.u;
}
static __device__ __forceinline__ float low_f(u64t v) {
  union { uint32_t u; float f; } c; c.u = (uint32_t)v;
  return c.f;
}

static __device__ __forceinline__ float qmac2(uint32_t q, float h0, float h1, float acc) {
  acc = fmaf((float)(short)(q & 0xffffu), h0, acc);
  return fmaf((float)(short)(q >> 16), h1, acc);
}

// precise softplus: max(x,0) + log1p(exp(-|x|))
static __device__ __forceinline__ float sp(float x) {
  return fmaxf(x, 0.f) + log1pf(expf(-fabsf(x)));
}

// LDS-only barrier: orders all LDS traffic, leaves global loads in flight.
static __device__ __forceinline__ void lbar() {
  asm volatile("s_waitcnt lgkmcnt(0)\n\ts_barrier" ::: "memory");
}

// np.searchsorted(kn, t, 'right') - 1, clipped to [0, 62]; 64 knots.
static __device__ __forceinline__ int seg_idx(const float* kn, float t) {
  int lo = 0, hi = 64;
  while (lo < hi) { int mid = (lo + hi) >> 1; if (kn[mid] <= t) lo = mid + 1; else hi = mid; }
  int jj = lo - 1;
  return jj < 0 ? 0 : (jj > 62 ? 62 : jj);
}

// ---- prep: per-row int16 quantization into chunk-tiled streaming layouts ----
__global__ void prep_kernel(const float* __restrict__ v_win,
                            const float* __restrict__ v_wmid,
                            const float* __restrict__ v_wout,
                            unsigned char* __restrict__ wsb) {
  float* scales = (float*)(wsb + SC_OFF);
  short* wv  = (short*)(wsb + WV_OFF);
  short* wm1 = (short*)(wsb + WM1_OFF);
  short* wl4 = (short*)(wsb + WL4_OFF);
  short* wm0 = (short*)(wsb + WM0_OFF);
  const int r = blockIdx.x, lane = threadIdx.x;
  const float* src;
  int n;
  if (r < 256)       { src = v_win  + (size_t)r * 128;                 n = 128; }
  else if (r < 512)  { src = v_wmid + 65536 + (size_t)(r - 256) * 256; n = 256; }
  else if (r < 2560) { src = v_wout + (size_t)(r - 512) * 256;         n = 256; }
  else               { src = v_wmid + (size_t)(r - 2560) * 256;        n = 256; }
  float m = 0.f;
  for (int i = lane; i < n; i += 64) m = fmaxf(m, fabsf(src[i]));
#pragma unroll
  for (int off = 32; off; off >>= 1) m = fmaxf(m, __shfl_xor(m, off));
  const float inv = (m > 0.f) ? 32767.f / m : 0.f;
  if (lane == 0) scales[r] = (m > 0.f) ? m / 32767.f : 1.f;
  for (int i = lane; i < n; i += 64) {
    short q = (short)rintf(src[i] * inv);
    if (r < 256) {
      int hf = i >> 6, c = (i & 63) >> 3, e = i & 7;
      wv[c * 4096 + (2 * r + hf) * 8 + e] = q;
    } else if (r < 512) {
      int row = r - 256, hf = i >> 7, c = (i & 127) >> 3, e = i & 7;
      wm1[c * 4096 + (2 * row + hf) * 8 + e] = q;
    } else if (r < 2560) {
      int row = r - 512;               // 0..2047; row = h*16 + d
      int h = row >> 4, d = row & 15;
      int s = h >> 6, h_loc = h & 63, dgrp = d >> 1, rs = d & 1;
      int t = h_loc * 8 + dgrp;        // 0..511
      int cc = i >> 3, e = i & 7;
      wl4[s * 262144 + ((rs * 32 + cc) * 512 + t) * 8 + e] = q;
    } else {
      int row = r - 2560;
      wm0[(size_t)row * 256 + i] = q;
    }
  }
}

__global__ void __launch_bounds__(NTHR)
ncde_kernel(const float* __restrict__ ts, const float* __restrict__ tsi,
            const float* __restrict__ obs, const float* __restrict__ tmax,
            const float* __restrict__ i_win, const float* __restrict__ i_bin,
            const float* __restrict__ i_wmid, const float* __restrict__ i_bmid,
            const float* __restrict__ i_wout, const float* __restrict__ i_bout,
            const float* __restrict__ v_wmid, const float* __restrict__ v_bin,
            const float* __restrict__ v_bmid, const float* __restrict__ v_bout,
            unsigned char* __restrict__ wsb, float* __restrict__ out) {
  __shared__ __align__(16) uint32_t s_m0[256][132];   // int16-pair m0, swizzled
  __shared__ __align__(16) float s_yin[128];
  __shared__ __align__(16) float s_h1[256];
  __shared__ __align__(16) float s_h2[256];
  __shared__ __align__(16) float s_h3[256];
  __shared__ __align__(16) float s_ts[64];
  __shared__ __align__(16) float s_kn[64];
  __shared__ float s_y[128];    // full ODE state (bit-identical in both blocks)
  __shared__ float s_k[128];    // latest k (own half local, partner via poll)
  __shared__ float s_ka[128];   // RK4 accumulator
  __shared__ float s_dx[16];
  __shared__ float s_x0[16];
  __shared__ unsigned char s_sj[128];

  const int t = threadIdx.x;
  const int bid = blockIdx.x;
  const int b = bid & 127;      // batch
  const int s = bid >> 7;       // half: s=0 rows h 0..63, s=1 rows 64..127
  const int o = t >> 1, half = t & 1;

  const float* scales = (const float*)(wsb + SC_OFF);
  const uint4* wvp  = ((const uint4*)(wsb + WV_OFF)) + t;
  const uint4* wm1p = ((const uint4*)(wsb + WM1_OFF)) + t;
  const uint4* wl4p = ((const uint4*)(wsb + WL4_OFF)) + s * 32768 + t;
  u64t* exb    = ((u64t*)(wsb + EX_OFF)) + (size_t)b * 256;
  u64t* ex_own = exb + s * 128;          // [2 banks][64]
  u64t* expart = exb + (1 - s) * 128;

  if (t < 64) { s_ts[t] = ts[b * 64 + t]; s_kn[t] = tsi[b * 64 + t]; }
  const float tm = tmax[b];
  const float bl1 = v_bin[o];
  const float bm0 = v_bmid[o];
  const float bm1 = v_bmid[256 + o];
  const float sc_wv = scales[o];
  const float sc_m1 = scales[256 + o];
  const float sc_m0 = scales[2560 + o];
  // L4: this thread's two rows r0 (even), r0+1
  const int r0 = ((s << 6) + (t >> 3)) * 16 + 2 * (t & 7);
  const float2 scl4 = *(const float2*)(scales + 512 + r0);
  const float2 vb2  = *(const float2*)(v_bout + r0);
  __syncthreads();

  // m0 -> LDS (coalesced u32 copy, quartet-breaking swizzle on cols)
  {
    const uint32_t* wm0u = (const uint32_t*)(wsb + WM0_OFF);
    for (int idx = t; idx < 32768; idx += NTHR) {
      int row = idx >> 7, k = idx & 127;
      s_m0[row][k ^ (((row >> 3) & 3) << 2)] = wm0u[idx];
    }
  }
  if (t < 127) {
    int li = t >> 1;
    float te = (t & 1) ? fmaf(0.5f, s_ts[li + 1] - s_ts[li], s_ts[li]) : s_ts[li];
    s_sj[t] = (unsigned char)seg_idx(s_kn, te);
  }
  __syncthreads();

  // ---------------- init MLP: y0 = MLP_i(x0) (redundant in both blocks) ----
  if (t < 16) {
    float t0 = s_ts[0];
    int sj = s_sj[0];
    float k0 = s_kn[sj], k1 = s_kn[sj + 1];
    float fr = (t0 - k0) / (k1 - k0);
    const float* ob = obs + ((size_t)b * 64 + sj) * 16 + t;
    s_x0[t] = fmaf(fr, ob[16] - ob[0], ob[0]);
  }
  __syncthreads();
  if (t < 256) {                       // L1i: o=t, 16 ins
    float acc = i_bin[t];
    const float* wr = i_win + (size_t)t * 16;
#pragma unroll
    for (int i = 0; i < 16; ++i) acc = fmaf(wr[i], s_x0[i], acc);
    s_h1[t] = sp(acc);
  }
  __syncthreads();
  {                                    // m0i: o, half over 128 ins
    float acc = 0.f;
    const float4* wq = (const float4*)(i_wmid + (size_t)o * 256 + half * 128);
    const float4* hp = (const float4*)(s_h1 + half * 128);
#pragma unroll
    for (int i = 0; i < 32; ++i) {
      float4 w = wq[i]; float4 hh = hp[i];
      acc = fmaf(w.x, hh.x, acc); acc = fmaf(w.y, hh.y, acc);
      acc = fmaf(w.z, hh.z, acc); acc = fmaf(w.w, hh.w, acc);
    }
    acc += __shfl_xor(acc, 1);
    if (!half) s_h2[o] = sp(acc + i_bmid[o]);
  }
  __syncthreads();
  {                                    // m1i
    float acc = 0.f;
    const float4* wq = (const float4*)(i_wmid + 65536 + (size_t)o * 256 + half * 128);
    const float4* hp = (const float4*)(s_h2 + half * 128);
#pragma unroll
    for (int i = 0; i < 32; ++i) {
      float4 w = wq[i]; float4 hh = hp[i];
      acc = fmaf(w.x, hh.x, acc); acc = fmaf(w.y, hh.y, acc);
      acc = fmaf(w.z, hh.z, acc); acc = fmaf(w.w, hh.w, acc);
    }
    acc += __shfl_xor(acc, 1);
    if (!half) s_h3[o] = sp(acc + i_bmid[256 + o]);
  }
  __syncthreads();
  {                                    // L4i: 128 rows; h=t>>2, quarter t&3
    float acc = 0.f;
    const float4* wq = (const float4*)(i_wout + (size_t)(t >> 2) * 256 + (t & 3) * 64);
    const float4* hp = (const float4*)(s_h3 + (t & 3) * 64);
#pragma unroll
    for (int i = 0; i < 16; ++i) {
      float4 w = wq[i]; float4 hh = hp[i];
      acc = fmaf(w.x, hh.x, acc); acc = fmaf(w.y, hh.y, acc);
      acc = fmaf(w.z, hh.z, acc); acc = fmaf(w.w, hh.w, acc);
    }
    acc += __shfl_xor(acc, 1);
    acc += __shfl_xor(acc, 2);
    if ((t & 3) == 0) {
      int h = t >> 2;
      float y0 = acc + i_bout[h];
      s_y[h] = y0;
      if (s == 0)
        out[(size_t)b * 8192 + h] = (s_ts[0] <= tm) ? y0 : -99.f;
    }
  }
  __syncthreads();

  // ---------------- RK4 over 63 intervals, paired half-split --------------
#pragma unroll 1
  for (int l = 0; l < 63; ++l) {
    const float dt = s_ts[l + 1] - s_ts[l];
    const float dtp = (l > 0) ? (s_ts[l] - s_ts[l - 1]) : 0.f;
#pragma unroll 1
    for (int e = 0; e < 4; ++e) {
      // ---- phase 0: merge k (own LDS / partner poll), update state, y_in --
      auto upd = [&](int h, float kv) {
        if (e == 0) {                  // l > 0: finish prev eval, start new
          float ka = s_ka[h] + kv;
          float yn = fmaf(dtp * (1.f / 6.f), ka, s_y[h]);
          s_y[h] = yn;
          s_yin[h] = yn;
          if (s == 0)
            out[(size_t)b * 8192 + (size_t)l * 128 + h] =
                (s_ts[l] <= tm) ? yn : -99.f;
        } else {
          float ka = (e == 1) ? kv : fmaf(2.f, kv, s_ka[h]);
          s_ka[h] = ka;
          float ce = (e == 3) ? 1.f : 0.5f;
          s_yin[h] = fmaf(ce * dt, kv, s_y[h]);
        }
      };
      if (l == 0 && e == 0) {
        if (t < 128) s_yin[t] = s_y[t];
      } else {
        const uint32_t tg = (uint32_t)(l * 4 + e);   // partner's last publish
        if (t < 64) {
          u64t* pw = expart + ((tg & 1) << 6) + t;
          u64t v = ld_coh8(pw);
          uint32_t n = 0;
          while ((uint32_t)(v >> 32) != tg) {
            if (n > 8) __builtin_amdgcn_s_sleep(8);
            else       __builtin_amdgcn_s_sleep(1);
            if (++n > (1u << 14)) break;   // bounded failsafe
            v = ld_coh8(pw);
          }
          upd((1 - s) * 64 + t, low_f(v));
        } else if (t < 128) {
          int ho = s * 64 + (t - 64);
          upd(ho, s_k[ho]);
        }
      }
      if (t >= 128 && t < 144) {      // dx(t_e)
        int d = t - 128;
        int ti = 2 * l + ((e == 0) ? 0 : ((e == 3) ? 2 : 1));
        int sj = s_sj[ti];
        const float* ob = obs + ((size_t)b * 64 + sj) * 16 + d;
        s_dx[d] = (ob[16] - ob[0]) / (s_kn[sj + 1] - s_kn[sj]);
      }
      lbar();
      // ---- L1 (streamed int16): row o, half over 64 y-ins ----
      {
        float acc = 0.f;
#pragma unroll
        for (int c = 0; c < 8; ++c) {
          uint4 w = wvp[c * 512];
          float4 ya = *(const float4*)(s_yin + half * 64 + 8 * c);
          float4 yb = *(const float4*)(s_yin + half * 64 + 8 * c + 4);
          acc = qmac2(w.x, ya.x, ya.y, acc);
          acc = qmac2(w.y, ya.z, ya.w, acc);
          acc = qmac2(w.z, yb.x, yb.y, acc);
          acc = qmac2(w.w, yb.z, yb.w, acc);
        }
        acc += __shfl_xor(acc, 1);
        if (!half) s_h1[o] = sp(acc * sc_wv + bl1);
      }
      lbar();
      // ---- m0 (LDS int16): row o, half over 128 ins ----
      {
        float acc = 0.f;
        const int swz = ((o >> 3) & 3) << 2;
        const uint32_t* wr = &s_m0[o][0];
#pragma unroll
        for (int k = 0; k < 16; ++k) {
          uint4 w = *(const uint4*)(wr + (((half * 64 + 4 * k)) ^ swz));
          float4 ha = *(const float4*)(s_h1 + half * 128 + 8 * k);
          float4 hb = *(const float4*)(s_h1 + half * 128 + 8 * k + 4);
          acc = qmac2(w.x, ha.x, ha.y, acc);
          acc = qmac2(w.y, ha.z, ha.w, acc);
          acc = qmac2(w.z, hb.x, hb.y, acc);
          acc = qmac2(w.w, hb.z, hb.w, acc);
        }
        acc += __shfl_xor(acc, 1);
        if (!half) s_h2[o] = sp(acc * sc_m0 + bm0);
      }
      lbar();
      // ---- m1 (streamed int16): row o, half over 128 ins ----
      {
        float acc = 0.f;
#pragma unroll 4
        for (int c = 0; c < 16; ++c) {
          uint4 w = wm1p[c * 512];
          float4 ha = *(const float4*)(s_h2 + half * 128 + 8 * c);
          float4 hb = *(const float4*)(s_h2 + half * 128 + 8 * c + 4);
          acc = qmac2(w.x, ha.x, ha.y, acc);
          acc = qmac2(w.y, ha.z, ha.w, acc);
          acc = qmac2(w.z, hb.x, hb.y, acc);
          acc = qmac2(w.w, hb.z, hb.w, acc);
        }
        acc += __shfl_xor(acc, 1);
        if (!half) s_h3[o] = sp(acc * sc_m1 + bm1);
      }
      lbar();
      // ---- L4 (streamed int16, 512KB half): 2 rows/thread (r0, r0+1) ----
      {
        float z0 = 0.f, z1 = 0.f;
#pragma unroll 4
        for (int cc = 0; cc < 32; ++cc) {
          float4 ha = *(const float4*)(s_h3 + 8 * cc);
          float4 hb = *(const float4*)(s_h3 + 8 * cc + 4);
          uint4 w0 = wl4p[cc * 512];
          uint4 w1 = wl4p[(32 + cc) * 512];
          z0 = qmac2(w0.x, ha.x, ha.y, z0); z0 = qmac2(w0.y, ha.z, ha.w, z0);
          z0 = qmac2(w0.z, hb.x, hb.y, z0); z0 = qmac2(w0.w, hb.z, hb.w, z0);
          z1 = qmac2(w1.x, ha.x, ha.y, z1); z1 = qmac2(w1.y, ha.z, ha.w, z1);
          z1 = qmac2(w1.z, hb.x, hb.y, z1); z1 = qmac2(w1.w, hb.z, hb.w, z1);
        }
        const int d0 = 2 * (t & 7);
        float kv;
        kv = tanhf(fmaf(z0, scl4.x, vb2.x)) * s_dx[d0];
        kv = fmaf(tanhf(fmaf(z1, scl4.y, vb2.y)), s_dx[d0 + 1], kv);
        kv += __shfl_xor(kv, 1);
        kv += __shfl_xor(kv, 2);
        kv += __shfl_xor(kv, 4);
        if ((t & 7) == 0) {
          const uint32_t T = (uint32_t)(l * 4 + e + 1);   // this publish
          int h_loc = t >> 3;
          s_k[(s << 6) + h_loc] = kv;
          st_coh8(ex_own + ((T & 1) << 6) + h_loc, pack_tf(kv, T));
        }
      }
      lbar();
    }
  }

  // -------- epilogue: consume final k (tag 252), write out row 63 ---------
  if (s == 0) {
    const float dtp = s_ts[63] - s_ts[62];
    if (t < 64) {
      u64t* pw = expart + t;               // tag 252 -> bank 0
      u64t v = ld_coh8(pw);
      uint32_t n = 0;
      while ((uint32_t)(v >> 32) != 252u) {
        if (n > 8) __builtin_amdgcn_s_sleep(8);
        else       __builtin_amdgcn_s_sleep(1);
        if (++n > (1u << 14)) break;
        v = ld_coh8(pw);
      }
      int h = 64 + t;                      // s==0 -> partner half is 64..127
      float ka = s_ka[h] + low_f(v);
      float yn = fmaf(dtp * (1.f / 6.f), ka, s_y[h]);
      out[(size_t)b * 8192 + 63 * 128 + h] = (s_ts[63] <= tm) ? yn : -99.f;
    } else if (t < 128) {
      int h = t - 64;                      // own half 0..63
      float ka = s_ka[h] + s_k[h];
      float yn = fmaf(dtp * (1.f / 6.f), ka, s_y[h]);
      out[(size_t)b * 8192 + 63 * 128 + h] = (s_ts[63] <= tm) ? yn : -99.f;
    }
  }
}

extern "C" void kernel_launch(void* const* d_in, const int* in_sizes, int n_in,
                              void* d_out, int out_size, void* d_ws, size_t ws_size,
                              hipStream_t stream) {
  const float* ts     = (const float*)d_in[0];
  const float* tsi    = (const float*)d_in[1];
  const float* obs    = (const float*)d_in[2];
  const float* tmaxp  = (const float*)d_in[3];
  const float* i_win  = (const float*)d_in[4];
  const float* i_bin  = (const float*)d_in[5];
  const float* i_wmid = (const float*)d_in[6];
  const float* i_bmid = (const float*)d_in[7];
  const float* i_wout = (const float*)d_in[8];
  const float* i_bout = (const float*)d_in[9];
  const float* v_win  = (const float*)d_in[10];
  const float* v_bin  = (const float*)d_in[11];
  const float* v_wmid = (const float*)d_in[12];
  const float* v_bmid = (const float*)d_in[13];
  const float* v_wout = (const float*)d_in[14];
  const float* v_bout = (const float*)d_in[15];

  unsigned char* wsb = (unsigned char*)d_ws;   // needs 1,649,664 B

  // zero the k-exchange region (tags restart each launch; graph-safe)
  size_t exbytes = 262144;
  if (EX_OFF + exbytes > ws_size) exbytes = (ws_size > EX_OFF) ? ws_size - EX_OFF : 0;
  (void)hipMemsetAsync(wsb + EX_OFF, 0, exbytes, stream);

  prep_kernel<<<dim3(2816), dim3(64), 0, stream>>>(v_win, v_wmid, v_wout, wsb);
  ncde_kernel<<<dim3(NB), dim3(NTHR), 0, stream>>>(
      ts, tsi, obs, tmaxp,
      i_win, i_bin, i_wmid, i_bmid, i_wout, i_bout,
      v_wmid, v_bin, v_bmid, v_bout,
      wsb, (float*)d_out);
}

// Round 19
// 2551.954 us; speedup vs baseline: 2.6003x; 1.1121x over previous
//
#include <hip/hip_runtime.h>
#include <stdint.h>

// Online Neural CDE — R19: R18 (2838us) + fast tanh/softplus (R10-proven
// numerics) + precomputed dx table in LDS (removes per-eval obs load from
// the critical path; bit-identical values).
// Architecture: pair-split. Batch b = blocks b (s=0) and b+128 (s=1),
// 512 threads each, 256 blocks = 256 CUs. Both blocks run L1/m0/m1
// redundantly on identical state; L4 split by h-half. Per sub-eval each
// block publishes its 64 k-values as tagged 8B words (value+epoch,
// double-banked); partner polls (pairwise, lockstep-covered, bounded).
// Only s=0 writes out. int16 weights + fp32 activations/state; lgkm-only
// in-loop barriers.

#define NB   256
#define NTHR 512

// d_ws byte layout (total 1,649,664 B)
#define SC_OFF   0u        // 2816 f32 scales
#define WV_OFF   11264u    // 64 KB
#define WM1_OFF  76800u    // 128 KB
#define WL4_OFF  207872u   // 1 MB (2 sets x 512 KB)
#define WM0_OFF  1256448u  // 128 KB
#define EX_OFF   1387520u  // 128 batches x 2 sets x 2 banks x 64 u64 = 256 KB

typedef unsigned long long u64t;

static __device__ __forceinline__ u64t ld_coh8(const u64t* p) {
  return __hip_atomic_load(p, __ATOMIC_RELAXED, __HIP_MEMORY_SCOPE_AGENT);
}
static __device__ __forceinline__ void st_coh8(u64t* p, u64t v) {
  __hip_atomic_store(p, v, __ATOMIC_RELAXED, __HIP_MEMORY_SCOPE_AGENT);
}
static __device__ __forceinline__ u64t pack_tf(float f, uint32_t tag) {
  union { float f; uint32_t u; } c; c.f = f;
  return ((u64t)tag << 32) | c.u;
}
static __device__ __forceinline__ float low_f(u64t v) {
  union { uint32_t u; float f; } c; c.u = (uint32_t)v;
  return c.f;
}

static __device__ __forceinline__ float qmac2(uint32_t q, float h0, float h1, float acc) {
  acc = fmaf((float)(short)(q & 0xffffu), h0, acc);
  return fmaf((float)(short)(q >> 16), h1, acc);
}

// fast softplus: max(x,0) + log(1+exp(-|x|)) via hardware exp2/log2
static __device__ __forceinline__ float sp_fast(float x) {
  return fmaxf(x, 0.f) + __logf(1.f + __expf(-fabsf(x)));
}
// precise softplus (init only)
static __device__ __forceinline__ float sp(float x) {
  return fmaxf(x, 0.f) + log1pf(expf(-fabsf(x)));
}
// fast tanh via __expf + v_rcp; saturates correctly for large |x| (R10-proven)
static __device__ __forceinline__ float tanh_fast(float x) {
  float ax = fabsf(x);
  float e = __expf(ax + ax);
  float t = 1.f - 2.f * __builtin_amdgcn_rcpf(e + 1.f);
  return __builtin_copysignf(t, x);
}

// LDS-only barrier: orders all LDS traffic, leaves global loads in flight.
static __device__ __forceinline__ void lbar() {
  asm volatile("s_waitcnt lgkmcnt(0)\n\ts_barrier" ::: "memory");
}

// np.searchsorted(kn, t, 'right') - 1, clipped to [0, 62]; 64 knots.
static __device__ __forceinline__ int seg_idx(const float* kn, float t) {
  int lo = 0, hi = 64;
  while (lo < hi) { int mid = (lo + hi) >> 1; if (kn[mid] <= t) lo = mid + 1; else hi = mid; }
  int jj = lo - 1;
  return jj < 0 ? 0 : (jj > 62 ? 62 : jj);
}

// ---- prep: per-row int16 quantization into chunk-tiled streaming layouts ----
__global__ void prep_kernel(const float* __restrict__ v_win,
                            const float* __restrict__ v_wmid,
                            const float* __restrict__ v_wout,
                            unsigned char* __restrict__ wsb) {
  float* scales = (float*)(wsb + SC_OFF);
  short* wv  = (short*)(wsb + WV_OFF);
  short* wm1 = (short*)(wsb + WM1_OFF);
  short* wl4 = (short*)(wsb + WL4_OFF);
  short* wm0 = (short*)(wsb + WM0_OFF);
  const int r = blockIdx.x, lane = threadIdx.x;
  const float* src;
  int n;
  if (r < 256)       { src = v_win  + (size_t)r * 128;                 n = 128; }
  else if (r < 512)  { src = v_wmid + 65536 + (size_t)(r - 256) * 256; n = 256; }
  else if (r < 2560) { src = v_wout + (size_t)(r - 512) * 256;         n = 256; }
  else               { src = v_wmid + (size_t)(r - 2560) * 256;        n = 256; }
  float m = 0.f;
  for (int i = lane; i < n; i += 64) m = fmaxf(m, fabsf(src[i]));
#pragma unroll
  for (int off = 32; off; off >>= 1) m = fmaxf(m, __shfl_xor(m, off));
  const float inv = (m > 0.f) ? 32767.f / m : 0.f;
  if (lane == 0) scales[r] = (m > 0.f) ? m / 32767.f : 1.f;
  for (int i = lane; i < n; i += 64) {
    short q = (short)rintf(src[i] * inv);
    if (r < 256) {
      int hf = i >> 6, c = (i & 63) >> 3, e = i & 7;
      wv[c * 4096 + (2 * r + hf) * 8 + e] = q;
    } else if (r < 512) {
      int row = r - 256, hf = i >> 7, c = (i & 127) >> 3, e = i & 7;
      wm1[c * 4096 + (2 * row + hf) * 8 + e] = q;
    } else if (r < 2560) {
      int row = r - 512;               // 0..2047; row = h*16 + d
      int h = row >> 4, d = row & 15;
      int s = h >> 6, h_loc = h & 63, dgrp = d >> 1, rs = d & 1;
      int t = h_loc * 8 + dgrp;        // 0..511
      int cc = i >> 3, e = i & 7;
      wl4[s * 262144 + ((rs * 32 + cc) * 512 + t) * 8 + e] = q;
    } else {
      int row = r - 2560;
      wm0[(size_t)row * 256 + i] = q;
    }
  }
}

__global__ void __launch_bounds__(NTHR)
ncde_kernel(const float* __restrict__ ts, const float* __restrict__ tsi,
            const float* __restrict__ obs, const float* __restrict__ tmax,
            const float* __restrict__ i_win, const float* __restrict__ i_bin,
            const float* __restrict__ i_wmid, const float* __restrict__ i_bmid,
            const float* __restrict__ i_wout, const float* __restrict__ i_bout,
            const float* __restrict__ v_wmid, const float* __restrict__ v_bin,
            const float* __restrict__ v_bmid, const float* __restrict__ v_bout,
            unsigned char* __restrict__ wsb, float* __restrict__ out) {
  __shared__ __align__(16) uint32_t s_m0[256][132];   // int16-pair m0, swizzled
  __shared__ __align__(16) float s_yin[128];
  __shared__ __align__(16) float s_h1[256];
  __shared__ __align__(16) float s_h2[256];
  __shared__ __align__(16) float s_h3[256];
  __shared__ __align__(16) float s_ts[64];
  __shared__ __align__(16) float s_kn[64];
  __shared__ __align__(16) float s_dxt[127][16];      // dx table per (ti, d)
  __shared__ float s_y[128];    // full ODE state (bit-identical in both blocks)
  __shared__ float s_k[128];    // latest k (own half local, partner via poll)
  __shared__ float s_ka[128];   // RK4 accumulator
  __shared__ float s_x0[16];
  __shared__ unsigned char s_sj[128];

  const int t = threadIdx.x;
  const int bid = blockIdx.x;
  const int b = bid & 127;      // batch
  const int s = bid >> 7;       // half: s=0 rows h 0..63, s=1 rows 64..127
  const int o = t >> 1, half = t & 1;

  const float* scales = (const float*)(wsb + SC_OFF);
  const uint4* wvp  = ((const uint4*)(wsb + WV_OFF)) + t;
  const uint4* wm1p = ((const uint4*)(wsb + WM1_OFF)) + t;
  const uint4* wl4p = ((const uint4*)(wsb + WL4_OFF)) + s * 32768 + t;
  u64t* exb    = ((u64t*)(wsb + EX_OFF)) + (size_t)b * 256;
  u64t* ex_own = exb + s * 128;          // [2 banks][64]
  u64t* expart = exb + (1 - s) * 128;

  if (t < 64) { s_ts[t] = ts[b * 64 + t]; s_kn[t] = tsi[b * 64 + t]; }
  const float tm = tmax[b];
  const float bl1 = v_bin[o];
  const float bm0 = v_bmid[o];
  const float bm1 = v_bmid[256 + o];
  const float sc_wv = scales[o];
  const float sc_m1 = scales[256 + o];
  const float sc_m0 = scales[2560 + o];
  // L4: this thread's two rows r0 (even), r0+1
  const int r0 = ((s << 6) + (t >> 3)) * 16 + 2 * (t & 7);
  const float2 scl4 = *(const float2*)(scales + 512 + r0);
  const float2 vb2  = *(const float2*)(v_bout + r0);
  __syncthreads();

  // m0 -> LDS (coalesced u32 copy, quartet-breaking swizzle on cols)
  {
    const uint32_t* wm0u = (const uint32_t*)(wsb + WM0_OFF);
    for (int idx = t; idx < 32768; idx += NTHR) {
      int row = idx >> 7, k = idx & 127;
      s_m0[row][k ^ (((row >> 3) & 3) << 2)] = wm0u[idx];
    }
  }
  if (t < 127) {
    int li = t >> 1;
    float te = (t & 1) ? fmaf(0.5f, s_ts[li + 1] - s_ts[li], s_ts[li]) : s_ts[li];
    s_sj[t] = (unsigned char)seg_idx(s_kn, te);
  }
  __syncthreads();

  // precompute dx table: s_dxt[ti][d] for ti in [0,127), d in [0,16)
  for (int idx = t; idx < 127 * 16; idx += NTHR) {
    int ti = idx >> 4, d = idx & 15;
    int sj = s_sj[ti];
    const float* ob = obs + ((size_t)b * 64 + sj) * 16 + d;
    s_dxt[ti][d] = (ob[16] - ob[0]) / (s_kn[sj + 1] - s_kn[sj]);
  }

  // ---------------- init MLP: y0 = MLP_i(x0) (redundant in both blocks) ----
  if (t < 16) {
    float t0 = s_ts[0];
    int sj = seg_idx(s_kn, t0);
    float k0 = s_kn[sj], k1 = s_kn[sj + 1];
    float fr = (t0 - k0) / (k1 - k0);
    const float* ob = obs + ((size_t)b * 64 + sj) * 16 + t;
    s_x0[t] = fmaf(fr, ob[16] - ob[0], ob[0]);
  }
  __syncthreads();
  if (t < 256) {                       // L1i: o=t, 16 ins
    float acc = i_bin[t];
    const float* wr = i_win + (size_t)t * 16;
#pragma unroll
    for (int i = 0; i < 16; ++i) acc = fmaf(wr[i], s_x0[i], acc);
    s_h1[t] = sp(acc);
  }
  __syncthreads();
  {                                    // m0i: o, half over 128 ins
    float acc = 0.f;
    const float4* wq = (const float4*)(i_wmid + (size_t)o * 256 + half * 128);
    const float4* hp = (const float4*)(s_h1 + half * 128);
#pragma unroll
    for (int i = 0; i < 32; ++i) {
      float4 w = wq[i]; float4 hh = hp[i];
      acc = fmaf(w.x, hh.x, acc); acc = fmaf(w.y, hh.y, acc);
      acc = fmaf(w.z, hh.z, acc); acc = fmaf(w.w, hh.w, acc);
    }
    acc += __shfl_xor(acc, 1);
    if (!half) s_h2[o] = sp(acc + i_bmid[o]);
  }
  __syncthreads();
  {                                    // m1i
    float acc = 0.f;
    const float4* wq = (const float4*)(i_wmid + 65536 + (size_t)o * 256 + half * 128);
    const float4* hp = (const float4*)(s_h2 + half * 128);
#pragma unroll
    for (int i = 0; i < 32; ++i) {
      float4 w = wq[i]; float4 hh = hp[i];
      acc = fmaf(w.x, hh.x, acc); acc = fmaf(w.y, hh.y, acc);
      acc = fmaf(w.z, hh.z, acc); acc = fmaf(w.w, hh.w, acc);
    }
    acc += __shfl_xor(acc, 1);
    if (!half) s_h3[o] = sp(acc + i_bmid[256 + o]);
  }
  __syncthreads();
  {                                    // L4i: 128 rows; h=t>>2, quarter t&3
    float acc = 0.f;
    const float4* wq = (const float4*)(i_wout + (size_t)(t >> 2) * 256 + (t & 3) * 64);
    const float4* hp = (const float4*)(s_h3 + (t & 3) * 64);
#pragma unroll
    for (int i = 0; i < 16; ++i) {
      float4 w = wq[i]; float4 hh = hp[i];
      acc = fmaf(w.x, hh.x, acc); acc = fmaf(w.y, hh.y, acc);
      acc = fmaf(w.z, hh.z, acc); acc = fmaf(w.w, hh.w, acc);
    }
    acc += __shfl_xor(acc, 1);
    acc += __shfl_xor(acc, 2);
    if ((t & 3) == 0) {
      int h = t >> 2;
      float y0 = acc + i_bout[h];
      s_y[h] = y0;
      if (s == 0)
        out[(size_t)b * 8192 + h] = (s_ts[0] <= tm) ? y0 : -99.f;
    }
  }
  __syncthreads();

  // ---------------- RK4 over 63 intervals, paired half-split --------------
#pragma unroll 1
  for (int l = 0; l < 63; ++l) {
    const float dt = s_ts[l + 1] - s_ts[l];
    const float dtp = (l > 0) ? (s_ts[l] - s_ts[l - 1]) : 0.f;
#pragma unroll 1
    for (int e = 0; e < 4; ++e) {
      const int ti = 2 * l + ((e == 0) ? 0 : ((e == 3) ? 2 : 1));
      // ---- phase 0: merge k (own LDS / partner poll), update state, y_in --
      auto upd = [&](int h, float kv) {
        if (e == 0) {                  // l > 0: finish prev eval, start new
          float ka = s_ka[h] + kv;
          float yn = fmaf(dtp * (1.f / 6.f), ka, s_y[h]);
          s_y[h] = yn;
          s_yin[h] = yn;
          if (s == 0)
            out[(size_t)b * 8192 + (size_t)l * 128 + h] =
                (s_ts[l] <= tm) ? yn : -99.f;
        } else {
          float ka = (e == 1) ? kv : fmaf(2.f, kv, s_ka[h]);
          s_ka[h] = ka;
          float ce = (e == 3) ? 1.f : 0.5f;
          s_yin[h] = fmaf(ce * dt, kv, s_y[h]);
        }
      };
      if (l == 0 && e == 0) {
        if (t < 128) s_yin[t] = s_y[t];
      } else {
        const uint32_t tg = (uint32_t)(l * 4 + e);   // partner's last publish
        if (t < 64) {
          u64t* pw = expart + ((tg & 1) << 6) + t;
          u64t v = ld_coh8(pw);
          uint32_t n = 0;
          while ((uint32_t)(v >> 32) != tg) {
            if (n > 8) __builtin_amdgcn_s_sleep(8);
            else       __builtin_amdgcn_s_sleep(1);
            if (++n > (1u << 14)) break;   // bounded failsafe
            v = ld_coh8(pw);
          }
          upd((1 - s) * 64 + t, low_f(v));
        } else if (t < 128) {
          int ho = s * 64 + (t - 64);
          upd(ho, s_k[ho]);
        }
      }
      lbar();
      // ---- L1 (streamed int16): row o, half over 64 y-ins ----
      {
        float acc = 0.f;
#pragma unroll
        for (int c = 0; c < 8; ++c) {
          uint4 w = wvp[c * 512];
          float4 ya = *(const float4*)(s_yin + half * 64 + 8 * c);
          float4 yb = *(const float4*)(s_yin + half * 64 + 8 * c + 4);
          acc = qmac2(w.x, ya.x, ya.y, acc);
          acc = qmac2(w.y, ya.z, ya.w, acc);
          acc = qmac2(w.z, yb.x, yb.y, acc);
          acc = qmac2(w.w, yb.z, yb.w, acc);
        }
        acc += __shfl_xor(acc, 1);
        if (!half) s_h1[o] = sp_fast(acc * sc_wv + bl1);
      }
      lbar();
      // ---- m0 (LDS int16): row o, half over 128 ins ----
      {
        float acc = 0.f;
        const int swz = ((o >> 3) & 3) << 2;
        const uint32_t* wr = &s_m0[o][0];
#pragma unroll
        for (int k = 0; k < 16; ++k) {
          uint4 w = *(const uint4*)(wr + (((half * 64 + 4 * k)) ^ swz));
          float4 ha = *(const float4*)(s_h1 + half * 128 + 8 * k);
          float4 hb = *(const float4*)(s_h1 + half * 128 + 8 * k + 4);
          acc = qmac2(w.x, ha.x, ha.y, acc);
          acc = qmac2(w.y, ha.z, ha.w, acc);
          acc = qmac2(w.z, hb.x, hb.y, acc);
          acc = qmac2(w.w, hb.z, hb.w, acc);
        }
        acc += __shfl_xor(acc, 1);
        if (!half) s_h2[o] = sp_fast(acc * sc_m0 + bm0);
      }
      lbar();
      // ---- m1 (streamed int16): row o, half over 128 ins ----
      {
        float acc = 0.f;
#pragma unroll 4
        for (int c = 0; c < 16; ++c) {
          uint4 w = wm1p[c * 512];
          float4 ha = *(const float4*)(s_h2 + half * 128 + 8 * c);
          float4 hb = *(const float4*)(s_h2 + half * 128 + 8 * c + 4);
          acc = qmac2(w.x, ha.x, ha.y, acc);
          acc = qmac2(w.y, ha.z, ha.w, acc);
          acc = qmac2(w.z, hb.x, hb.y, acc);
          acc = qmac2(w.w, hb.z, hb.w, acc);
        }
        acc += __shfl_xor(acc, 1);
        if (!half) s_h3[o] = sp_fast(acc * sc_m1 + bm1);
      }
      lbar();
      // ---- L4 (streamed int16, 512KB half): 2 rows/thread (r0, r0+1) ----
      {
        float z0 = 0.f, z1 = 0.f;
#pragma unroll 4
        for (int cc = 0; cc < 32; ++cc) {
          float4 ha = *(const float4*)(s_h3 + 8 * cc);
          float4 hb = *(const float4*)(s_h3 + 8 * cc + 4);
          uint4 w0 = wl4p[cc * 512];
          uint4 w1 = wl4p[(32 + cc) * 512];
          z0 = qmac2(w0.x, ha.x, ha.y, z0); z0 = qmac2(w0.y, ha.z, ha.w, z0);
          z0 = qmac2(w0.z, hb.x, hb.y, z0); z0 = qmac2(w0.w, hb.z, hb.w, z0);
          z1 = qmac2(w1.x, ha.x, ha.y, z1); z1 = qmac2(w1.y, ha.z, ha.w, z1);
          z1 = qmac2(w1.z, hb.x, hb.y, z1); z1 = qmac2(w1.w, hb.z, hb.w, z1);
        }
        const int d0 = 2 * (t & 7);
        float kv;
        kv = tanh_fast(fmaf(z0, scl4.x, vb2.x)) * s_dxt[ti][d0];
        kv = fmaf(tanh_fast(fmaf(z1, scl4.y, vb2.y)), s_dxt[ti][d0 + 1], kv);
        kv += __shfl_xor(kv, 1);
        kv += __shfl_xor(kv, 2);
        kv += __shfl_xor(kv, 4);
        if ((t & 7) == 0) {
          const uint32_t T = (uint32_t)(l * 4 + e + 1);   // this publish
          int h_loc = t >> 3;
          s_k[(s << 6) + h_loc] = kv;
          st_coh8(ex_own + ((T & 1) << 6) + h_loc, pack_tf(kv, T));
        }
      }
      lbar();
    }
  }

  // -------- epilogue: consume final k (tag 252), write out row 63 ---------
  if (s == 0) {
    const float dtp = s_ts[63] - s_ts[62];
    if (t < 64) {
      u64t* pw = expart + t;               // tag 252 -> bank 0
      u64t v = ld_coh8(pw);
      uint32_t n = 0;
      while ((uint32_t)(v >> 32) != 252u) {
        if (n > 8) __builtin_amdgcn_s_sleep(8);
        else       __builtin_amdgcn_s_sleep(1);
        if (++n > (1u << 14)) break;
        v = ld_coh8(pw);
      }
      int h = 64 + t;                      // s==0 -> partner half is 64..127
      float ka = s_ka[h] + low_f(v);
      float yn = fmaf(dtp * (1.f / 6.f), ka, s_y[h]);
      out[(size_t)b * 8192 + 63 * 128 + h] = (s_ts[63] <= tm) ? yn : -99.f;
    } else if (t < 128) {
      int h = t - 64;                      // own half 0..63
      float ka = s_ka[h] + s_k[h];
      float yn = fmaf(dtp * (1.f / 6.f), ka, s_y[h]);
      out[(size_t)b * 8192 + 63 * 128 + h] = (s_ts[63] <= tm) ? yn : -99.f;
    }
  }
}

extern "C" void kernel_launch(void* const* d_in, const int* in_sizes, int n_in,
                              void* d_out, int out_size, void* d_ws, size_t ws_size,
                              hipStream_t stream) {
  const float* ts     = (const float*)d_in[0];
  const float* tsi    = (const float*)d_in[1];
  const float* obs    = (const float*)d_in[2];
  const float* tmaxp  = (const float*)d_in[3];
  const float* i_win  = (const float*)d_in[4];
  const float* i_bin  = (const float*)d_in[5];
  const float* i_wmid = (const float*)d_in[6];
  const float* i_bmid = (const float*)d_in[7];
  const float* i_wout = (const float*)d_in[8];
  const float* i_bout = (const float*)d_in[9];
  const float* v_win  = (const float*)d_in[10];
  const float* v_bin  = (const float*)d_in[11];
  const float* v_wmid = (const float*)d_in[12];
  const float* v_bmid = (const float*)d_in[13];
  const float* v_wout = (const float*)d_in[14];
  const float* v_bout = (const float*)d_in[15];

  unsigned char* wsb = (unsigned char*)d_ws;   // needs 1,649,664 B

  // zero the k-exchange region (tags restart each launch; graph-safe)
  size_t exbytes = 262144;
  if (EX_OFF + exbytes > ws_size) exbytes = (ws_size > EX_OFF) ? ws_size - EX_OFF : 0;
  (void)hipMemsetAsync(wsb + EX_OFF, 0, exbytes, stream);

  prep_kernel<<<dim3(2816), dim3(64), 0, stream>>>(v_win, v_wmid, v_wout, wsb);
  ncde_kernel<<<dim3(NB), dim3(NTHR), 0, stream>>>(
      ts, tsi, obs, tmaxp,
      i_win, i_bin, i_wmid, i_bmid, i_wout, i_bout,
      v_wmid, v_bin, v_bmid, v_bout,
      wsb, (float*)d_out);
}